// Round 5
// baseline (3187.272 us; speedup 1.0000x reference)
//
#include <hip/hip_runtime.h>
#include <hip/hip_bf16.h>
#include <math.h>

typedef unsigned short u16;
typedef __attribute__((ext_vector_type(8))) short bf16x8;
typedef __attribute__((ext_vector_type(4))) float f32x4;

__device__ __forceinline__ u16 f2b(float x) {
  union { float f; unsigned u; } c; c.f = x;
  unsigned r = c.u + 0x7FFFu + ((c.u >> 16) & 1u);
  return (u16)(r >> 16);
}
__device__ __forceinline__ float b2f(u16 u) {
  union { unsigned u; float f; } c; c.u = ((unsigned)u) << 16;
  return c.f;
}

__device__ __forceinline__ void gl_lds16(const u16* g, u16* l) {
  __builtin_amdgcn_global_load_lds(
      (const __attribute__((address_space(1))) void*)g,
      (__attribute__((address_space(3))) void*)l, 16, 0, 0);
}

// ---------------- transpose + fp32->bf16 convert: W[K][N] -> WT[Npad][KApad] ---------
__global__ void tconv(const float* __restrict__ W, u16* __restrict__ WT,
                      int K, int N, int KApad, int Npad) {
  __shared__ float tile[32][33];
  int z = blockIdx.z;
  W += (size_t)z * K * N;
  WT += (size_t)z * Npad * KApad;
  int n0 = blockIdx.x * 32, k0 = blockIdx.y * 32;
  int tx = threadIdx.x, ty = threadIdx.y;
  for (int i = 0; i < 4; ++i) {
    int k = k0 + ty + i * 8, n = n0 + tx;
    tile[ty + i * 8][tx] = (k < K && n < N) ? W[(size_t)k * N + n] : 0.f;
  }
  __syncthreads();
  for (int i = 0; i < 4; ++i) {
    int n = n0 + ty + i * 8, k = k0 + tx;
    WT[(size_t)n * KApad + k] = f2b(tile[tx][ty + i * 8]);
  }
}

// ---------------- conditioning ----------------
__global__ void cond1(const int* __restrict__ ts, const float* __restrict__ Wt1,
                      const float* __restrict__ bt1, float* __restrict__ t1) {
  __shared__ float pe[512];
  int b = blockIdx.x, tid = threadIdx.x;
  float pos = (float)ts[b];
  int i2 = tid >> 1;
  float dv = expf(-0.0359778920780e0f * (float)i2);
  float ang = pos * dv;
  pe[tid] = (tid & 1) ? cosf(ang) : sinf(ang);
  __syncthreads();
  float acc = bt1[tid];
  for (int k = 0; k < 512; ++k) acc += pe[k] * Wt1[k * 512 + tid];
  t1[b * 512 + tid] = acc / (1.f + expf(-acc));  // silu
}

__global__ void cond2(const float* __restrict__ t1buf, const float* __restrict__ Wt2,
                      const float* __restrict__ bt2, const float* __restrict__ enc,
                      const float* __restrict__ Wtxt, const float* __restrict__ btxt,
                      float* __restrict__ emb) {
  __shared__ float a[512], m[512];
  int b = blockIdx.x, tid = threadIdx.x;
  a[tid] = t1buf[b * 512 + tid];
  float s = 0.f;
  for (int j = 0; j < 20; ++j) s += enc[((size_t)(b * 20 + j)) * 512 + tid];
  m[tid] = s * 0.05f;
  __syncthreads();
  float acc = bt2[tid] + btxt[tid];
  for (int k = 0; k < 512; ++k) acc += a[k] * Wt2[k * 512 + tid] + m[k] * Wtxt[k * 512 + tid];
  emb[b * 512 + tid] = acc;
}

// ---------------- rope table: [512][32] float2(cos,sin) ----------------
__global__ void rope_tab(float2* __restrict__ rt) {
  int idx = blockIdx.x * 256 + threadIdx.x;  // 16384
  int t = idx >> 5, i = idx & 31;
  float ang = (float)t * __expf(-0.28782313662f * (float)i);
  float sn, cn;
  sincosf(ang, &sn, &cn);
  rt[idx] = make_float2(cn, sn);
}

// ---------------- x fp32 -> bf16 with K-pad 150->192 ----------------
__global__ void xconv(const float* __restrict__ x, u16* __restrict__ xb) {
  int idx = blockIdx.x * 256 + threadIdx.x;  // 16384*192
  int mrow = idx / 192, kk = idx - mrow * 192;
  float v = (kk < 150) ? x[(size_t)mrow * 150 + kk] : 0.f;
  xb[idx] = f2b(v);
}

// ---------------- LayerNorm: h fp32 [row][512] -> y bf16 ----------------
__global__ __launch_bounds__(256) void ln_kernel(const float* __restrict__ h,
                                                 const float* __restrict__ g,
                                                 const float* __restrict__ be,
                                                 u16* __restrict__ y) {
  int row = blockIdx.x, tid = threadIdx.x;
  const float* hr = h + (size_t)row * 512;
  float v0 = hr[tid], v1 = hr[tid + 256];
  int lane = tid & 63, w = tid >> 6;
  float s = v0 + v1;
  for (int o = 32; o; o >>= 1) s += __shfl_down(s, o, 64);
  __shared__ float red[4], red2[4];
  if (!lane) red[w] = s;
  __syncthreads();
  float mean = (red[0] + red[1] + red[2] + red[3]) * (1.f / 512.f);
  float d0 = v0 - mean, d1 = v1 - mean;
  float vs = d0 * d0 + d1 * d1;
  for (int o = 32; o; o >>= 1) vs += __shfl_down(vs, o, 64);
  if (!lane) red2[w] = vs;
  __syncthreads();
  float var = (red2[0] + red2[1] + red2[2] + red2[3]) * (1.f / 512.f);
  float rs = rsqrtf(var + 1e-5f);
  y[(size_t)row * 512 + tid] = f2b(d0 * rs * g[tid] + be[tid]);
  y[(size_t)row * 512 + tid + 256] = f2b(d1 * rs * g[tid + 256] + be[tid + 256]);
}

// ---------------- flash attention v2, MFMA bf16 ----------------
// grid (8 qtiles, 8 heads, 32 batch), 256 threads = 4 waves; wave w owns q-rows w*16..+15.
// qk layout: [b*512+t][1024] (Q cols 0..511 pre-scaled+rope'd, K cols 512..1023 rope'd).
// LDS: Qs 8K + KVs 16K (K then V^T) + Ps 16K = 40 KB -> 4 blocks/CU.
__global__ __launch_bounds__(256) void attn_mfma2(const u16* __restrict__ qk,
                                                  const u16* __restrict__ vt,
                                                  u16* __restrict__ o) {
  __shared__ u16 Qs[64 * 64];
  __shared__ u16 KVs[128 * 64];
  __shared__ u16 Ps[64 * 128];
  const int tid = threadIdx.x;
  const int qt = blockIdx.x, h = blockIdx.y, b = blockIdx.z;
  const int lane = tid & 63, w = tid >> 6;
  const int q = lane >> 4, c16 = lane & 15;

  // stage Q tile 64x64 (async)
  const size_t qbase = (size_t)(b * 512 + qt * 64) * 1024 + h * 64;
  {
    int row0 = tid >> 3, cs = tid & 7;
#pragma unroll
    for (int rep = 0; rep < 2; ++rep) {
      int r2 = rep * 32 + row0;
      int g = cs ^ (r2 & 7);
      gl_lds16(qk + qbase + (size_t)r2 * 1024 + g * 8, Qs + rep * 2048 + tid * 8);
    }
  }

  f32x4 o_acc[4];
  float m_st[4], l_st[4];
#pragma unroll
  for (int jd = 0; jd < 4; ++jd) o_acc[jd] = (f32x4){0.f, 0.f, 0.f, 0.f};
#pragma unroll
  for (int r = 0; r < 4; ++r) { m_st[r] = -1e30f; l_st[r] = 0.f; }

  const size_t kbase = (size_t)b * 512 * 1024 + 512 + h * 64;
  const size_t vtbase = ((size_t)(b * 8 + h) * 64) * 512;

  for (int kt = 0; kt < 4; ++kt) {
    if (kt) __syncthreads();  // prior PV reads of KVs/Ps done
    // stage K tile 128x64 (async)
    {
      int row0 = tid >> 3, cs = tid & 7;
#pragma unroll
      for (int rep = 0; rep < 4; ++rep) {
        int r2 = rep * 32 + row0;
        int g = cs ^ (r2 & 7);
        gl_lds16(qk + kbase + (size_t)(kt * 128 + r2) * 1024 + g * 8,
                 KVs + rep * 2048 + tid * 8);
      }
    }
    __syncthreads();  // K (and Q) visible

    // S = Q K^T  (1 m-tile x 8 n-tiles, K=64 -> 2 steps)
    f32x4 s_acc[8];
#pragma unroll
    for (int j = 0; j < 8; ++j) s_acc[j] = (f32x4){0.f, 0.f, 0.f, 0.f};
#pragma unroll
    for (int ka = 0; ka < 2; ++ka) {
      bf16x8 af, bf[8];
      {
        int row = w * 16 + c16;
        af = *(const bf16x8*)(Qs + row * 64 + (((ka * 4 + q) ^ (row & 7)) * 8));
      }
#pragma unroll
      for (int j = 0; j < 8; ++j) {
        int row = j * 16 + c16;
        bf[j] = *(const bf16x8*)(KVs + row * 64 + (((ka * 4 + q) ^ (row & 7)) * 8));
      }
#pragma unroll
      for (int j = 0; j < 8; ++j)
        s_acc[j] = __builtin_amdgcn_mfma_f32_16x16x32_bf16(af, bf[j], s_acc[j], 0, 0, 0);
    }
    __syncthreads();  // K reads done -> KVs reusable for V

    // stage V^T tile 64x128 (async); overlaps softmax below
    // per rep = 256 lanes x 16B = 2048 u16 -> stride rep*2048
    {
      int vr0 = tid >> 4, cc = tid & 15;
#pragma unroll
      for (int rep = 0; rep < 4; ++rep) {
        int row = rep * 16 + vr0;
        int g2 = cc ^ (row & 15);
        gl_lds16(vt + vtbase + (size_t)row * 512 + kt * 128 + g2 * 8,
                 KVs + rep * 2048 + tid * 8);
      }
    }

    // online softmax in registers (scores pre-scaled via Q)
#pragma unroll
    for (int r = 0; r < 4; ++r) {
      float mx = s_acc[0][r];
#pragma unroll
      for (int j = 1; j < 8; ++j) mx = fmaxf(mx, s_acc[j][r]);
      mx = fmaxf(mx, __shfl_xor(mx, 1, 64));
      mx = fmaxf(mx, __shfl_xor(mx, 2, 64));
      mx = fmaxf(mx, __shfl_xor(mx, 4, 64));
      mx = fmaxf(mx, __shfl_xor(mx, 8, 64));
      float mn = fmaxf(m_st[r], mx);
      float al = __expf(m_st[r] - mn);
      m_st[r] = mn;
      float sum = 0.f;
#pragma unroll
      for (int j = 0; j < 8; ++j) {
        float p = __expf(s_acc[j][r] - mn);
        s_acc[j][r] = p;
        sum += p;
      }
      sum += __shfl_xor(sum, 1, 64);
      sum += __shfl_xor(sum, 2, 64);
      sum += __shfl_xor(sum, 4, 64);
      sum += __shfl_xor(sum, 8, 64);
      l_st[r] = l_st[r] * al + sum;
#pragma unroll
      for (int jd = 0; jd < 4; ++jd) o_acc[jd][r] *= al;
    }

    // write P (bf16, swizzled A-layout source)
#pragma unroll
    for (int j = 0; j < 8; ++j)
#pragma unroll
      for (int r = 0; r < 4; ++r) {
        int prow = w * 16 + q * 4 + r;
        int col = j * 16 + c16;
        int cp = col >> 3;
        Ps[prow * 128 + ((cp ^ (prow & 15)) * 8) + (col & 7)] = f2b(s_acc[j][r]);
      }
    __syncthreads();  // P written, V visible

    // O += P V  (128 keys -> 4 steps)
#pragma unroll
    for (int s = 0; s < 4; ++s) {
      bf16x8 af, bv[4];
      {
        int row = w * 16 + c16;
        af = *(const bf16x8*)(Ps + row * 128 + (((s * 4 + q) ^ (row & 15)) * 8));
      }
#pragma unroll
      for (int jd = 0; jd < 4; ++jd) {
        int row = jd * 16 + c16;
        bv[jd] = *(const bf16x8*)(KVs + row * 128 + (((s * 4 + q) ^ (row & 15)) * 8));
      }
#pragma unroll
      for (int jd = 0; jd < 4; ++jd)
        o_acc[jd] = __builtin_amdgcn_mfma_f32_16x16x32_bf16(af, bv[jd], o_acc[jd], 0, 0, 0);
    }
  }

  // epilogue: normalize and store
#pragma unroll
  for (int r = 0; r < 4; ++r) {
    float inv = 1.f / l_st[r];
    int trow = qt * 64 + w * 16 + q * 4 + r;
#pragma unroll
    for (int jd = 0; jd < 4; ++jd)
      o[(size_t)(b * 512 + trow) * 512 + h * 64 + jd * 16 + c16] = f2b(o_acc[jd][r] * inv);
  }
}

// ---------------- bf16 MFMA GEMM: C = A[M,KA] * BT[N,KA]^T + bias, epilogues ------
// grid: x = M-tile (BM rows), y = N-tile (128 cols).  BM in {128, 256}.
// MODE 0: fp32 out = acc + bias + emb[row/512]   (input proj; BM=128)
// MODE 2: fp32 out = aux(h) + acc + bias         (residual; BM=128)
// MODE 3: bf16 out = gelu(acc + bias)            (FF1; BM=256)
// MODE 4: fp32 out[row*150+col] = acc + bias, col<150 (final; BM=128)
// MODE 5: qkv fused: rope(Q*0.125,K) -> Cout [row][1024]; V transposed -> aux2 (BM=256)
// MODE 6: MODE 2 + bf16 copy into aux2 (last-layer FF2 + hconv fusion; BM=128)
template <int MODE, int BM>
__global__ __launch_bounds__(256) void gemm_bf16(
    const u16* __restrict__ A, const u16* __restrict__ BT,
    const float* __restrict__ bias, const float* aux, void* aux2, void* Cout,
    int KA, int ldc) {
  __shared__ u16 As[BM * 64];
  __shared__ u16 Bs[128 * 64];
  const int tid = threadIdx.x;
  const int tileM = blockIdx.x * BM;
  const int tileN = blockIdx.y * 128;
  const int lane = tid & 63, w = tid >> 6;
  const int q = lane >> 4, c16 = lane & 15;
  constexpr int NJ = (BM == 256) ? 8 : 4;
  const int mwb = (BM == 256) ? (w * 64) : ((w >> 1) * 64);
  const int nwb = (BM == 256) ? 0 : ((w & 1) * 64);

  f32x4 acc[4][NJ];
#pragma unroll
  for (int i = 0; i < 4; ++i)
#pragma unroll
    for (int j = 0; j < NJ; ++j) acc[i][j] = (f32x4){0.f, 0.f, 0.f, 0.f};

  const int rowA0 = tid >> 3;  // 0..31
  const int cs = tid & 7;
  const int KT = KA >> 6;
  for (int kt = 0; kt < KT; ++kt) {
    __syncthreads();
#pragma unroll
    for (int rep = 0; rep < BM / 32; ++rep) {
      int row = rep * 32 + rowA0;
      int g = cs ^ (row & 7);
      gl_lds16(A + (size_t)(tileM + row) * KA + kt * 64 + g * 8,
               (u16*)((char*)As + rep * 4096 + tid * 16));
    }
#pragma unroll
    for (int rep = 0; rep < 4; ++rep) {
      int row = rep * 32 + rowA0;
      int g = cs ^ (row & 7);
      gl_lds16(BT + (size_t)(tileN + row) * KA + kt * 64 + g * 8,
               (u16*)((char*)Bs + rep * 4096 + tid * 16));
    }
    __syncthreads();
#pragma unroll
    for (int ks = 0; ks < 2; ++ks) {
      bf16x8 af[4], bfr[NJ];
#pragma unroll
      for (int i = 0; i < 4; ++i) {
        int m = mwb + i * 16 + c16;
        int ca = (ks * 4 + q) ^ (m & 7);
        af[i] = *(const bf16x8*)((const char*)As + m * 128 + ca * 16);
      }
#pragma unroll
      for (int j = 0; j < NJ; ++j) {
        int n = nwb + j * 16 + c16;
        int cb = (ks * 4 + q) ^ (n & 7);
        bfr[j] = *(const bf16x8*)((const char*)Bs + n * 128 + cb * 16);
      }
#pragma unroll
      for (int i = 0; i < 4; ++i)
#pragma unroll
        for (int j = 0; j < NJ; ++j)
          acc[i][j] = __builtin_amdgcn_mfma_f32_16x16x32_bf16(af[i], bfr[j], acc[i][j], 0, 0, 0);
    }
  }

  if (MODE == 5) {
    // fused qkv epilogue: rope on Q (scaled) and K; transpose-store V. BM=256, NJ=8.
    const float2* rt = (const float2*)aux;
    u16* qk = (u16*)Cout;
    u16* vtp = (u16*)aux2;
    if (tileN < 1024) {
      // Q/K tile: pairs (jp, jp+2) for jp in {0,1,4,5}; cols d and d+32
      const int jps[4] = {0, 1, 4, 5};
#pragma unroll
      for (int i = 0; i < 4; ++i) {
        int row = tileM + mwb + i * 16 + q * 4;
        int t0 = row & 511;
#pragma unroll
        for (int jj = 0; jj < 4; ++jj) {
          int jp = jps[jj];
          int colA = tileN + jp * 16 + c16;
          int colB = colA + 32;
          int d31 = colA & 31;
          float scl = (colA < 512) ? 0.125f : 1.f;
          float bA = bias[colA], bB = bias[colB];
#pragma unroll
          for (int r = 0; r < 4; ++r) {
            float2 cs2 = rt[(t0 + r) * 32 + d31];
            float x1 = acc[i][jp][r] + bA;
            float x2 = acc[i][jp + 2][r] + bB;
            size_t rbase = (size_t)(row + r) * 1024;
            qk[rbase + colA] = f2b((x1 * cs2.x - x2 * cs2.y) * scl);
            qk[rbase + colB] = f2b((x2 * cs2.x + x1 * cs2.y) * scl);
          }
        }
      }
    } else {
      // V tile: transpose-store, 4 rows packed per ushort4
#pragma unroll
      for (int i = 0; i < 4; ++i) {
        int row = tileM + mwb + i * 16 + q * 4;
        int bb = row >> 9, t0 = row & 511;
#pragma unroll
        for (int j = 0; j < NJ; ++j) {
          int col = tileN + j * 16 + c16;
          int hh = (col - 1024) >> 6, d = col & 63;
          float bv2 = bias[col];
          ushort4 pk;
          pk.x = f2b(acc[i][j][0] + bv2);
          pk.y = f2b(acc[i][j][1] + bv2);
          pk.z = f2b(acc[i][j][2] + bv2);
          pk.w = f2b(acc[i][j][3] + bv2);
          *(ushort4*)(vtp + ((size_t)((bb * 8 + hh) * 64 + d)) * 512 + t0) = pk;
        }
      }
    }
    return;
  }

  // generic epilogues
#pragma unroll
  for (int i = 0; i < 4; ++i) {
#pragma unroll
    for (int j = 0; j < NJ; ++j) {
      int col = tileN + nwb + j * 16 + c16;
      float bv = (MODE == 4) ? 0.f : bias[col];
#pragma unroll
      for (int r = 0; r < 4; ++r) {
        int row = tileM + mwb + i * 16 + q * 4 + r;
        float v = acc[i][j][r] + bv;
        if (MODE == 0) {
          ((float*)Cout)[(size_t)row * ldc + col] = v + aux[(row >> 9) * 512 + col];
        } else if (MODE == 2) {
          size_t idx = (size_t)row * ldc + col;
          ((float*)Cout)[idx] = aux[idx] + v;
        } else if (MODE == 3) {
          float gl = 0.5f * v * (1.f + erff(v * 0.70710678118f));
          ((u16*)Cout)[(size_t)row * ldc + col] = f2b(gl);
        } else if (MODE == 4) {
          if (col < 150) ((float*)Cout)[(size_t)row * 150 + col] = acc[i][j][r] + bias[col];
        } else if (MODE == 6) {
          size_t idx = (size_t)row * ldc + col;
          float v2 = aux[idx] + v;
          ((float*)Cout)[idx] = v2;
          ((u16*)aux2)[idx] = f2b(v2);
        }
      }
    }
  }
}

// ---------------- launch ----------------
extern "C" void kernel_launch(void* const* d_in, const int* in_sizes, int n_in,
                              void* d_out, int out_size, void* d_ws, size_t ws_size,
                              hipStream_t stream) {
  const float* x = (const float*)d_in[0];
  const int* tsteps = (const int*)d_in[1];
  const float* enc = (const float*)d_in[2];
  const float* W_in = (const float*)d_in[3];
  const float* b_in = (const float*)d_in[4];
  const float* W_t1 = (const float*)d_in[5];
  const float* b_t1 = (const float*)d_in[6];
  const float* W_t2 = (const float*)d_in[7];
  const float* b_t2 = (const float*)d_in[8];
  const float* W_txt = (const float*)d_in[9];
  const float* b_txt = (const float*)d_in[10];
  const float* ln1_g = (const float*)d_in[11];
  const float* ln1_b = (const float*)d_in[12];
  const float* Wqkv = (const float*)d_in[13];
  const float* bqkv = (const float*)d_in[14];
  const float* Wo = (const float*)d_in[15];
  const float* bo = (const float*)d_in[16];
  const float* ln2_g = (const float*)d_in[17];
  const float* ln2_b = (const float*)d_in[18];
  const float* W1 = (const float*)d_in[19];
  const float* b1 = (const float*)d_in[20];
  const float* W2 = (const float*)d_in[21];
  const float* b2 = (const float*)d_in[22];
  const float* W_out = (const float*)d_in[23];
  const float* b_out = (const float*)d_in[24];

  char* ws = (char*)d_ws;
  u16* WT_in = (u16*)(ws + 0);              // 512*192
  u16* WT_qkv = (u16*)(ws + 196608);        // 8*1536*512
  u16* WT_o = (u16*)(ws + 12779520);        // 8*512*512
  u16* WT_1 = (u16*)(ws + 16973824);        // 8*2048*512
  u16* WT_2 = (u16*)(ws + 33751040);        // 8*512*2048
  u16* WT_out = (u16*)(ws + 50528256);      // 256*512
  u16* xb = (u16*)(ws + 50790400);          // 16384*192
  float* hf = (float*)(ws + 57081856);      // 16384*512 f32
  u16* yb = (u16*)(ws + 90636288);          // 16384*512
  u16* qkvb = (u16*)(ws + 107413504);       // 16384*1024 (Q,K rope'd); tail reused:
  float2* rtab = (float2*)(ws + 107413504 + 33554432);  // 512*32 float2 = 128 KB
  u16* ob = (u16*)(ws + 157745152);         // 16384*512
  u16* ffb = (u16*)(ws + 174522368);        // 16384*2048
  u16* hb = (u16*)(ws + 241631232);         // 16384*512 (final h bf16; idle during layers)
  u16* vtb = hb;                            // aliased: V^T [b][h][64][512], layer-loop only
  float* embf = (float*)(ws + 258408448);   // 32*512 f32
  float* t1c = (float*)(ws + 258473984);    // 32*512 f32

  dim3 tb(32, 8);
  tconv<<<dim3(16, 6, 1), tb, 0, stream>>>(W_in, WT_in, 150, 512, 192, 512);
  tconv<<<dim3(48, 16, 8), tb, 0, stream>>>(Wqkv, WT_qkv, 512, 1536, 512, 1536);
  tconv<<<dim3(16, 16, 8), tb, 0, stream>>>(Wo, WT_o, 512, 512, 512, 512);
  tconv<<<dim3(64, 16, 8), tb, 0, stream>>>(W1, WT_1, 512, 2048, 512, 2048);
  tconv<<<dim3(16, 64, 8), tb, 0, stream>>>(W2, WT_2, 2048, 512, 2048, 512);
  tconv<<<dim3(8, 16, 1), tb, 0, stream>>>(W_out, WT_out, 512, 150, 512, 256);

  cond1<<<32, 512, 0, stream>>>(tsteps, W_t1, b_t1, t1c);
  cond2<<<32, 512, 0, stream>>>(t1c, W_t2, b_t2, enc, W_txt, b_txt, embf);
  rope_tab<<<64, 256, 0, stream>>>(rtab);
  xconv<<<12288, 256, 0, stream>>>(x, xb);

  // h = x @ W_in + b_in + emb   (grid: x=M-tiles, y=N-tiles)
  gemm_bf16<0, 128><<<dim3(128, 4), 256, 0, stream>>>(xb, WT_in, b_in, embf, nullptr, hf, 192, 512);

  for (int l = 0; l < 8; ++l) {
    ln_kernel<<<16384, 256, 0, stream>>>(hf, ln1_g + l * 512, ln1_b + l * 512, yb);
    gemm_bf16<5, 256><<<dim3(64, 12), 256, 0, stream>>>(yb, WT_qkv + (size_t)l * 1536 * 512,
                                                        bqkv + l * 1536, (const float*)rtab,
                                                        vtb, qkvb, 512, 1024);
    attn_mfma2<<<dim3(8, 8, 32), 256, 0, stream>>>(qkvb, vtb, ob);
    gemm_bf16<2, 128><<<dim3(128, 4), 256, 0, stream>>>(ob, WT_o + (size_t)l * 512 * 512,
                                                        bo + l * 512, hf, nullptr, hf, 512, 512);
    ln_kernel<<<16384, 256, 0, stream>>>(hf, ln2_g + l * 512, ln2_b + l * 512, yb);
    gemm_bf16<3, 256><<<dim3(64, 16), 256, 0, stream>>>(yb, WT_1 + (size_t)l * 2048 * 512,
                                                        b1 + l * 2048, nullptr, nullptr, ffb, 512, 2048);
    if (l < 7) {
      gemm_bf16<2, 128><<<dim3(128, 4), 256, 0, stream>>>(ffb, WT_2 + (size_t)l * 512 * 2048,
                                                          b2 + l * 512, hf, nullptr, hf, 2048, 512);
    } else {
      gemm_bf16<6, 128><<<dim3(128, 4), 256, 0, stream>>>(ffb, WT_2 + (size_t)l * 512 * 2048,
                                                          b2 + l * 512, hf, hb, hf, 2048, 512);
    }
  }

  gemm_bf16<4, 128><<<dim3(128, 2), 256, 0, stream>>>(hb, WT_out, b_out, nullptr, nullptr, d_out, 512, 150);
}

// Round 6
// 2770.936 us; speedup vs baseline: 1.1503x; 1.1503x over previous
//
#include <hip/hip_runtime.h>
#include <hip/hip_bf16.h>
#include <math.h>

typedef unsigned short u16;
typedef __attribute__((ext_vector_type(8))) short bf16x8;
typedef __attribute__((ext_vector_type(4))) float f32x4;

__device__ __forceinline__ u16 f2b(float x) {
  union { float f; unsigned u; } c; c.f = x;
  unsigned r = c.u + 0x7FFFu + ((c.u >> 16) & 1u);
  return (u16)(r >> 16);
}
__device__ __forceinline__ float b2f(u16 u) {
  union { unsigned u; float f; } c; c.u = ((unsigned)u) << 16;
  return c.f;
}

__device__ __forceinline__ void gl_lds16(const u16* g, u16* l) {
  __builtin_amdgcn_global_load_lds(
      (const __attribute__((address_space(1))) void*)g,
      (__attribute__((address_space(3))) void*)l, 16, 0, 0);
}

// ---------------- transpose + fp32->bf16 convert: W[K][N] -> WT[Npad][KApad] ---------
__global__ void tconv(const float* __restrict__ W, u16* __restrict__ WT,
                      int K, int N, int KApad, int Npad) {
  __shared__ float tile[32][33];
  int z = blockIdx.z;
  W += (size_t)z * K * N;
  WT += (size_t)z * Npad * KApad;
  int n0 = blockIdx.x * 32, k0 = blockIdx.y * 32;
  int tx = threadIdx.x, ty = threadIdx.y;
  for (int i = 0; i < 4; ++i) {
    int k = k0 + ty + i * 8, n = n0 + tx;
    tile[ty + i * 8][tx] = (k < K && n < N) ? W[(size_t)k * N + n] : 0.f;
  }
  __syncthreads();
  for (int i = 0; i < 4; ++i) {
    int n = n0 + ty + i * 8, k = k0 + tx;
    WT[(size_t)n * KApad + k] = f2b(tile[tx][ty + i * 8]);
  }
}

// ---------------- conditioning ----------------
__global__ void cond1(const int* __restrict__ ts, const float* __restrict__ Wt1,
                      const float* __restrict__ bt1, float* __restrict__ t1) {
  __shared__ float pe[512];
  int b = blockIdx.x, tid = threadIdx.x;
  float pos = (float)ts[b];
  int i2 = tid >> 1;
  float dv = expf(-0.0359778920780e0f * (float)i2);
  float ang = pos * dv;
  pe[tid] = (tid & 1) ? cosf(ang) : sinf(ang);
  __syncthreads();
  float acc = bt1[tid];
  for (int k = 0; k < 512; ++k) acc += pe[k] * Wt1[k * 512 + tid];
  t1[b * 512 + tid] = acc / (1.f + expf(-acc));  // silu
}

__global__ void cond2(const float* __restrict__ t1buf, const float* __restrict__ Wt2,
                      const float* __restrict__ bt2, const float* __restrict__ enc,
                      const float* __restrict__ Wtxt, const float* __restrict__ btxt,
                      float* __restrict__ emb) {
  __shared__ float a[512], m[512];
  int b = blockIdx.x, tid = threadIdx.x;
  a[tid] = t1buf[b * 512 + tid];
  float s = 0.f;
  for (int j = 0; j < 20; ++j) s += enc[((size_t)(b * 20 + j)) * 512 + tid];
  m[tid] = s * 0.05f;
  __syncthreads();
  float acc = bt2[tid] + btxt[tid];
  for (int k = 0; k < 512; ++k) acc += a[k] * Wt2[k * 512 + tid] + m[k] * Wtxt[k * 512 + tid];
  emb[b * 512 + tid] = acc;
}

// ---------------- rope table: [512][32] float2(cos,sin) ----------------
__global__ void rope_tab(float2* __restrict__ rt) {
  int idx = blockIdx.x * 256 + threadIdx.x;  // 16384
  int t = idx >> 5, i = idx & 31;
  float ang = (float)t * __expf(-0.28782313662f * (float)i);
  float sn, cn;
  sincosf(ang, &sn, &cn);
  rt[idx] = make_float2(cn, sn);
}

// ---------------- x fp32 -> bf16 with K-pad 150->192 ----------------
__global__ void xconv(const float* __restrict__ x, u16* __restrict__ xb) {
  int idx = blockIdx.x * 256 + threadIdx.x;  // 16384*192
  int mrow = idx / 192, kk = idx - mrow * 192;
  float v = (kk < 150) ? x[(size_t)mrow * 150 + kk] : 0.f;
  xb[idx] = f2b(v);
}

// ---------------- LayerNorm: h fp32 [row][512] -> y bf16 ----------------
__global__ __launch_bounds__(256) void ln_kernel(const float* __restrict__ h,
                                                 const float* __restrict__ g,
                                                 const float* __restrict__ be,
                                                 u16* __restrict__ y) {
  int row = blockIdx.x, tid = threadIdx.x;
  const float* hr = h + (size_t)row * 512;
  float v0 = hr[tid], v1 = hr[tid + 256];
  int lane = tid & 63, w = tid >> 6;
  float s = v0 + v1;
  for (int o = 32; o; o >>= 1) s += __shfl_down(s, o, 64);
  __shared__ float red[4], red2[4];
  if (!lane) red[w] = s;
  __syncthreads();
  float mean = (red[0] + red[1] + red[2] + red[3]) * (1.f / 512.f);
  float d0 = v0 - mean, d1 = v1 - mean;
  float vs = d0 * d0 + d1 * d1;
  for (int o = 32; o; o >>= 1) vs += __shfl_down(vs, o, 64);
  if (!lane) red2[w] = vs;
  __syncthreads();
  float var = (red2[0] + red2[1] + red2[2] + red2[3]) * (1.f / 512.f);
  float rs = rsqrtf(var + 1e-5f);
  y[(size_t)row * 512 + tid] = f2b(d0 * rs * g[tid] + be[tid]);
  y[(size_t)row * 512 + tid + 256] = f2b(d1 * rs * g[tid + 256] + be[tid + 256]);
}

// ---------------- flash attention v2, MFMA bf16 ----------------
// grid (8 qtiles, 8 heads, 32 batch), 256 threads = 4 waves; wave w owns q-rows w*16..+15.
// qk layout: [b*512+t][1024] (Q cols 0..511 pre-scaled+rope'd, K cols 512..1023 rope'd).
// LDS: Qs 8K + KVs 16K (K then V^T) + Ps 16K = 40 KB -> 4 blocks/CU.
__global__ __launch_bounds__(256) void attn_mfma2(const u16* __restrict__ qk,
                                                  const u16* __restrict__ vt,
                                                  u16* __restrict__ o) {
  __shared__ u16 Qs[64 * 64];
  __shared__ u16 KVs[128 * 64];
  __shared__ u16 Ps[64 * 128];
  const int tid = threadIdx.x;
  const int qt = blockIdx.x, h = blockIdx.y, b = blockIdx.z;
  const int lane = tid & 63, w = tid >> 6;
  const int q = lane >> 4, c16 = lane & 15;

  // stage Q tile 64x64 (async)
  const size_t qbase = (size_t)(b * 512 + qt * 64) * 1024 + h * 64;
  {
    int row0 = tid >> 3, cs = tid & 7;
#pragma unroll
    for (int rep = 0; rep < 2; ++rep) {
      int r2 = rep * 32 + row0;
      int g = cs ^ (r2 & 7);
      gl_lds16(qk + qbase + (size_t)r2 * 1024 + g * 8, Qs + rep * 2048 + tid * 8);
    }
  }

  f32x4 o_acc[4];
  float m_st[4], l_st[4];
#pragma unroll
  for (int jd = 0; jd < 4; ++jd) o_acc[jd] = (f32x4){0.f, 0.f, 0.f, 0.f};
#pragma unroll
  for (int r = 0; r < 4; ++r) { m_st[r] = -1e30f; l_st[r] = 0.f; }

  const size_t kbase = (size_t)b * 512 * 1024 + 512 + h * 64;
  const size_t vtbase = ((size_t)(b * 8 + h) * 64) * 512;

  for (int kt = 0; kt < 4; ++kt) {
    if (kt) __syncthreads();  // prior PV reads of KVs/Ps done
    // stage K tile 128x64 (async)
    {
      int row0 = tid >> 3, cs = tid & 7;
#pragma unroll
      for (int rep = 0; rep < 4; ++rep) {
        int r2 = rep * 32 + row0;
        int g = cs ^ (r2 & 7);
        gl_lds16(qk + kbase + (size_t)(kt * 128 + r2) * 1024 + g * 8,
                 KVs + rep * 2048 + tid * 8);
      }
    }
    __syncthreads();  // K (and Q) visible

    // S = Q K^T  (1 m-tile x 8 n-tiles, K=64 -> 2 steps)
    f32x4 s_acc[8];
#pragma unroll
    for (int j = 0; j < 8; ++j) s_acc[j] = (f32x4){0.f, 0.f, 0.f, 0.f};
#pragma unroll
    for (int ka = 0; ka < 2; ++ka) {
      bf16x8 af, bf[8];
      {
        int row = w * 16 + c16;
        af = *(const bf16x8*)(Qs + row * 64 + (((ka * 4 + q) ^ (row & 7)) * 8));
      }
#pragma unroll
      for (int j = 0; j < 8; ++j) {
        int row = j * 16 + c16;
        bf[j] = *(const bf16x8*)(KVs + row * 64 + (((ka * 4 + q) ^ (row & 7)) * 8));
      }
#pragma unroll
      for (int j = 0; j < 8; ++j)
        s_acc[j] = __builtin_amdgcn_mfma_f32_16x16x32_bf16(af, bf[j], s_acc[j], 0, 0, 0);
    }
    __syncthreads();  // K reads done -> KVs reusable for V

    // stage V^T tile 64x128 (async); per rep = 256 lanes x 16B = 2048 u16
    {
      int vr0 = tid >> 4, cc = tid & 15;
#pragma unroll
      for (int rep = 0; rep < 4; ++rep) {
        int row = rep * 16 + vr0;
        int g2 = cc ^ (row & 15);
        gl_lds16(vt + vtbase + (size_t)row * 512 + kt * 128 + g2 * 8,
                 KVs + rep * 2048 + tid * 8);
      }
    }

    // online softmax in registers (scores pre-scaled via Q)
#pragma unroll
    for (int r = 0; r < 4; ++r) {
      float mx = s_acc[0][r];
#pragma unroll
      for (int j = 1; j < 8; ++j) mx = fmaxf(mx, s_acc[j][r]);
      mx = fmaxf(mx, __shfl_xor(mx, 1, 64));
      mx = fmaxf(mx, __shfl_xor(mx, 2, 64));
      mx = fmaxf(mx, __shfl_xor(mx, 4, 64));
      mx = fmaxf(mx, __shfl_xor(mx, 8, 64));
      float mn = fmaxf(m_st[r], mx);
      float al = __expf(m_st[r] - mn);
      m_st[r] = mn;
      float sum = 0.f;
#pragma unroll
      for (int j = 0; j < 8; ++j) {
        float p = __expf(s_acc[j][r] - mn);
        s_acc[j][r] = p;
        sum += p;
      }
      sum += __shfl_xor(sum, 1, 64);
      sum += __shfl_xor(sum, 2, 64);
      sum += __shfl_xor(sum, 4, 64);
      sum += __shfl_xor(sum, 8, 64);
      l_st[r] = l_st[r] * al + sum;
#pragma unroll
      for (int jd = 0; jd < 4; ++jd) o_acc[jd][r] *= al;
    }

    // write P (bf16, swizzled A-layout source)
#pragma unroll
    for (int j = 0; j < 8; ++j)
#pragma unroll
      for (int r = 0; r < 4; ++r) {
        int prow = w * 16 + q * 4 + r;
        int col = j * 16 + c16;
        int cp = col >> 3;
        Ps[prow * 128 + ((cp ^ (prow & 15)) * 8) + (col & 7)] = f2b(s_acc[j][r]);
      }
    __syncthreads();  // P written, V visible

    // O += P V  (128 keys -> 4 steps)
#pragma unroll
    for (int s = 0; s < 4; ++s) {
      bf16x8 af, bv[4];
      {
        int row = w * 16 + c16;
        af = *(const bf16x8*)(Ps + row * 128 + (((s * 4 + q) ^ (row & 15)) * 8));
      }
#pragma unroll
      for (int jd = 0; jd < 4; ++jd) {
        int row = jd * 16 + c16;
        bv[jd] = *(const bf16x8*)(KVs + row * 128 + (((s * 4 + q) ^ (row & 15)) * 8));
      }
#pragma unroll
      for (int jd = 0; jd < 4; ++jd)
        o_acc[jd] = __builtin_amdgcn_mfma_f32_16x16x32_bf16(af, bv[jd], o_acc[jd], 0, 0, 0);
    }
  }

  // epilogue: normalize and store
#pragma unroll
  for (int r = 0; r < 4; ++r) {
    float inv = 1.f / l_st[r];
    int trow = qt * 64 + w * 16 + q * 4 + r;
#pragma unroll
    for (int jd = 0; jd < 4; ++jd)
      o[(size_t)(b * 512 + trow) * 512 + h * 64 + jd * 16 + c16] = f2b(o_acc[jd][r] * inv);
  }
}

// ---------------- bf16 MFMA GEMM: C = A[128-tile,KA] * BT[BN-tile,KA]^T + bias ------
// grid: x = N-tile (BN cols), y = M-tile (128 rows).  BN in {64, 128}.
// Register budget note (R5 lesson): acc AGPRs + arch VGPRs must stay <=128/wave
// for 4 waves/SIMD. BN=64 -> acc[4][2]=32 AGPR. BN=128 -> acc[4][4]=64 AGPR.
// MODE 0: fp32 out = acc + bias + emb[row/512]   (input proj; BN=64)
// MODE 2: fp32 out = aux(h) + acc + bias         (residual; BN=64)
// MODE 3: bf16 out = gelu(acc + bias)            (FF1; BN=128)
// MODE 4: fp32 out[row*150+col] = acc + bias, col<150 (final; BN=64)
// MODE 5: qkv fused: rope(Q*0.125,K) -> Cout [row][1024]; V^T -> aux2 (BN=128)
// MODE 6: MODE 2 + bf16 copy into aux2 (last-layer FF2 + hconv fusion; BN=64)
template <int MODE, int BN>
__global__ __launch_bounds__(256) void gemm_bf16(
    const u16* __restrict__ A, const u16* __restrict__ BT,
    const float* __restrict__ bias, const float* aux, void* aux2, void* Cout,
    int KA, int ldc) {
  __shared__ u16 As[128 * 64];
  __shared__ u16 Bs[BN * 64];
  const int tid = threadIdx.x;
  const int tileN = blockIdx.x * BN;
  const int tileM = blockIdx.y * 128;
  const int lane = tid & 63, w = tid >> 6;
  const int q = lane >> 4, c16 = lane & 15;
  constexpr int NJ = BN / 32;
  const int mw = (w >> 1) * 64;
  const int nw = (w & 1) * (BN / 2);

  f32x4 acc[4][NJ];
#pragma unroll
  for (int i = 0; i < 4; ++i)
#pragma unroll
    for (int j = 0; j < NJ; ++j) acc[i][j] = (f32x4){0.f, 0.f, 0.f, 0.f};

  const int rowA0 = tid >> 3;  // 0..31
  const int cs = tid & 7;
  const int KT = KA >> 6;
  for (int kt = 0; kt < KT; ++kt) {
    __syncthreads();
#pragma unroll
    for (int rep = 0; rep < 4; ++rep) {
      int row = rep * 32 + rowA0;
      int g = cs ^ (row & 7);
      gl_lds16(A + (size_t)(tileM + row) * KA + kt * 64 + g * 8,
               (u16*)((char*)As + rep * 4096 + tid * 16));
    }
#pragma unroll
    for (int rep = 0; rep < BN / 32; ++rep) {
      int row = rep * 32 + rowA0;
      int g = cs ^ (row & 7);
      gl_lds16(BT + (size_t)(tileN + row) * KA + kt * 64 + g * 8,
               (u16*)((char*)Bs + rep * 4096 + tid * 16));
    }
    __syncthreads();
#pragma unroll
    for (int ks = 0; ks < 2; ++ks) {
      bf16x8 af[4], bfr[NJ];
#pragma unroll
      for (int i = 0; i < 4; ++i) {
        int m = mw + i * 16 + c16;
        int ca = (ks * 4 + q) ^ (m & 7);
        af[i] = *(const bf16x8*)((const char*)As + m * 128 + ca * 16);
      }
#pragma unroll
      for (int j = 0; j < NJ; ++j) {
        int n = nw + j * 16 + c16;
        int cb = (ks * 4 + q) ^ (n & 7);
        bfr[j] = *(const bf16x8*)((const char*)Bs + n * 128 + cb * 16);
      }
#pragma unroll
      for (int i = 0; i < 4; ++i)
#pragma unroll
        for (int j = 0; j < NJ; ++j)
          acc[i][j] = __builtin_amdgcn_mfma_f32_16x16x32_bf16(af[i], bfr[j], acc[i][j], 0, 0, 0);
    }
  }

  if (MODE == 5) {
    // fused qkv epilogue (BN=128, NJ=4): rope on Q (scaled) and K; transpose-store V.
    const float2* rt = (const float2*)aux;
    u16* qk = (u16*)Cout;
    u16* vtp = (u16*)aux2;
#pragma unroll
    for (int i = 0; i < 4; ++i) {
      int row = tileM + mw + i * 16 + q * 4;
      int bb = row >> 9, t0 = row & 511;
#pragma unroll
      for (int jp = 0; jp < 2; ++jp) {
        int colA = tileN + nw + jp * 16 + c16;
        if (colA < 1024) {
          int colB = colA + 32;
          int d31 = colA & 31;
          float scl = (colA < 512) ? 0.125f : 1.f;
          float bA = bias[colA], bB = bias[colB];
#pragma unroll
          for (int r = 0; r < 4; ++r) {
            float2 cs2 = rt[(t0 + r) * 32 + d31];
            float x1 = acc[i][jp][r] + bA;
            float x2 = acc[i][jp + 2][r] + bB;
            size_t rbase = (size_t)(row + r) * 1024;
            qk[rbase + colA] = f2b((x1 * cs2.x - x2 * cs2.y) * scl);
            qk[rbase + colB] = f2b((x2 * cs2.x + x1 * cs2.y) * scl);
          }
        } else {
#pragma unroll
          for (int jj = jp; jj < 4; jj += 2) {
            int col = tileN + nw + jj * 16 + c16;
            int hh = (col - 1024) >> 6, d = col & 63;
            float bv2 = bias[col];
            ushort4 pk;
            pk.x = f2b(acc[i][jj][0] + bv2);
            pk.y = f2b(acc[i][jj][1] + bv2);
            pk.z = f2b(acc[i][jj][2] + bv2);
            pk.w = f2b(acc[i][jj][3] + bv2);
            *(ushort4*)(vtp + ((size_t)((bb * 8 + hh) * 64 + d)) * 512 + t0) = pk;
          }
        }
      }
    }
    return;
  }

  // generic epilogues
#pragma unroll
  for (int i = 0; i < 4; ++i) {
#pragma unroll
    for (int j = 0; j < NJ; ++j) {
      int col = tileN + nw + j * 16 + c16;
      float bv = (MODE == 4) ? 0.f : bias[col];
#pragma unroll
      for (int r = 0; r < 4; ++r) {
        int row = tileM + mw + i * 16 + q * 4 + r;
        float v = acc[i][j][r] + bv;
        if (MODE == 0) {
          ((float*)Cout)[(size_t)row * ldc + col] = v + aux[(row >> 9) * 512 + col];
        } else if (MODE == 2) {
          size_t idx = (size_t)row * ldc + col;
          ((float*)Cout)[idx] = aux[idx] + v;
        } else if (MODE == 3) {
          float gl = 0.5f * v * (1.f + erff(v * 0.70710678118f));
          ((u16*)Cout)[(size_t)row * ldc + col] = f2b(gl);
        } else if (MODE == 4) {
          if (col < 150) ((float*)Cout)[(size_t)row * 150 + col] = acc[i][j][r] + bias[col];
        } else if (MODE == 6) {
          size_t idx = (size_t)row * ldc + col;
          float v2 = aux[idx] + v;
          ((float*)Cout)[idx] = v2;
          ((u16*)aux2)[idx] = f2b(v2);
        }
      }
    }
  }
}

// ---------------- launch ----------------
extern "C" void kernel_launch(void* const* d_in, const int* in_sizes, int n_in,
                              void* d_out, int out_size, void* d_ws, size_t ws_size,
                              hipStream_t stream) {
  const float* x = (const float*)d_in[0];
  const int* tsteps = (const int*)d_in[1];
  const float* enc = (const float*)d_in[2];
  const float* W_in = (const float*)d_in[3];
  const float* b_in = (const float*)d_in[4];
  const float* W_t1 = (const float*)d_in[5];
  const float* b_t1 = (const float*)d_in[6];
  const float* W_t2 = (const float*)d_in[7];
  const float* b_t2 = (const float*)d_in[8];
  const float* W_txt = (const float*)d_in[9];
  const float* b_txt = (const float*)d_in[10];
  const float* ln1_g = (const float*)d_in[11];
  const float* ln1_b = (const float*)d_in[12];
  const float* Wqkv = (const float*)d_in[13];
  const float* bqkv = (const float*)d_in[14];
  const float* Wo = (const float*)d_in[15];
  const float* bo = (const float*)d_in[16];
  const float* ln2_g = (const float*)d_in[17];
  const float* ln2_b = (const float*)d_in[18];
  const float* W1 = (const float*)d_in[19];
  const float* b1 = (const float*)d_in[20];
  const float* W2 = (const float*)d_in[21];
  const float* b2 = (const float*)d_in[22];
  const float* W_out = (const float*)d_in[23];
  const float* b_out = (const float*)d_in[24];

  char* ws = (char*)d_ws;
  u16* WT_in = (u16*)(ws + 0);              // 512*192
  u16* WT_qkv = (u16*)(ws + 196608);        // 8*1536*512
  u16* WT_o = (u16*)(ws + 12779520);        // 8*512*512
  u16* WT_1 = (u16*)(ws + 16973824);        // 8*2048*512
  u16* WT_2 = (u16*)(ws + 33751040);        // 8*512*2048
  u16* WT_out = (u16*)(ws + 50528256);      // 256*512
  u16* xb = (u16*)(ws + 50790400);          // 16384*192
  float* hf = (float*)(ws + 57081856);      // 16384*512 f32
  u16* yb = (u16*)(ws + 90636288);          // 16384*512
  u16* qkvb = (u16*)(ws + 107413504);       // 16384*1024 (Q,K rope'd); tail reused:
  float2* rtab = (float2*)(ws + 107413504 + 33554432);  // 512*32 float2 = 128 KB
  u16* ob = (u16*)(ws + 157745152);         // 16384*512
  u16* ffb = (u16*)(ws + 174522368);        // 16384*2048
  u16* hb = (u16*)(ws + 241631232);         // 16384*512 (final h bf16; idle during layers)
  u16* vtb = hb;                            // aliased: V^T [b][h][64][512], layer-loop only
  float* embf = (float*)(ws + 258408448);   // 32*512 f32
  float* t1c = (float*)(ws + 258473984);    // 32*512 f32

  dim3 tb(32, 8);
  tconv<<<dim3(16, 6, 1), tb, 0, stream>>>(W_in, WT_in, 150, 512, 192, 512);
  tconv<<<dim3(48, 16, 8), tb, 0, stream>>>(Wqkv, WT_qkv, 512, 1536, 512, 1536);
  tconv<<<dim3(16, 16, 8), tb, 0, stream>>>(Wo, WT_o, 512, 512, 512, 512);
  tconv<<<dim3(64, 16, 8), tb, 0, stream>>>(W1, WT_1, 512, 2048, 512, 2048);
  tconv<<<dim3(16, 64, 8), tb, 0, stream>>>(W2, WT_2, 2048, 512, 2048, 512);
  tconv<<<dim3(8, 16, 1), tb, 0, stream>>>(W_out, WT_out, 512, 150, 512, 256);

  cond1<<<32, 512, 0, stream>>>(tsteps, W_t1, b_t1, t1c);
  cond2<<<32, 512, 0, stream>>>(t1c, W_t2, b_t2, enc, W_txt, b_txt, embf);
  rope_tab<<<64, 256, 0, stream>>>(rtab);
  xconv<<<12288, 256, 0, stream>>>(x, xb);

  // h = x @ W_in + b_in + emb   (grid: x=N-tiles, y=M-tiles)
  gemm_bf16<0, 64><<<dim3(8, 128), 256, 0, stream>>>(xb, WT_in, b_in, embf, nullptr, hf, 192, 512);

  for (int l = 0; l < 8; ++l) {
    ln_kernel<<<16384, 256, 0, stream>>>(hf, ln1_g + l * 512, ln1_b + l * 512, yb);
    gemm_bf16<5, 128><<<dim3(12, 128), 256, 0, stream>>>(yb, WT_qkv + (size_t)l * 1536 * 512,
                                                         bqkv + l * 1536, (const float*)rtab,
                                                         vtb, qkvb, 512, 1024);
    attn_mfma2<<<dim3(8, 8, 32), 256, 0, stream>>>(qkvb, vtb, ob);
    gemm_bf16<2, 64><<<dim3(8, 128), 256, 0, stream>>>(ob, WT_o + (size_t)l * 512 * 512,
                                                       bo + l * 512, hf, nullptr, hf, 512, 512);
    ln_kernel<<<16384, 256, 0, stream>>>(hf, ln2_g + l * 512, ln2_b + l * 512, yb);
    gemm_bf16<3, 128><<<dim3(16, 128), 256, 0, stream>>>(yb, WT_1 + (size_t)l * 2048 * 512,
                                                         b1 + l * 2048, nullptr, nullptr, ffb, 512, 2048);
    if (l < 7) {
      gemm_bf16<2, 64><<<dim3(8, 128), 256, 0, stream>>>(ffb, WT_2 + (size_t)l * 512 * 2048,
                                                         b2 + l * 512, hf, nullptr, hf, 2048, 512);
    } else {
      gemm_bf16<6, 64><<<dim3(8, 128), 256, 0, stream>>>(ffb, WT_2 + (size_t)l * 512 * 2048,
                                                         b2 + l * 512, hf, hb, hf, 2048, 512);
    }
  }

  gemm_bf16<4, 64><<<dim3(4, 128), 256, 0, stream>>>(hb, WT_out, b_out, nullptr, nullptr, d_out, 512, 150);
}

// Round 7
// 2436.515 us; speedup vs baseline: 1.3081x; 1.1373x over previous
//
#include <hip/hip_runtime.h>
#include <hip/hip_bf16.h>
#include <math.h>

typedef unsigned short u16;
typedef __attribute__((ext_vector_type(8))) short bf16x8;
typedef __attribute__((ext_vector_type(4))) float f32x4;

__device__ __forceinline__ u16 f2b(float x) {
  union { float f; unsigned u; } c; c.f = x;
  unsigned r = c.u + 0x7FFFu + ((c.u >> 16) & 1u);
  return (u16)(r >> 16);
}
__device__ __forceinline__ float b2f(u16 u) {
  union { unsigned u; float f; } c; c.u = ((unsigned)u) << 16;
  return c.f;
}

__device__ __forceinline__ void gl_lds16(const u16* g, u16* l) {
  __builtin_amdgcn_global_load_lds(
      (const __attribute__((address_space(1))) void*)g,
      (__attribute__((address_space(3))) void*)l, 16, 0, 0);
}

// ---------------- transpose + fp32->bf16 convert: W[K][N] -> WT[Npad][KApad] ---------
__global__ void tconv(const float* __restrict__ W, u16* __restrict__ WT,
                      int K, int N, int KApad, int Npad) {
  __shared__ float tile[32][33];
  int z = blockIdx.z;
  W += (size_t)z * K * N;
  WT += (size_t)z * Npad * KApad;
  int n0 = blockIdx.x * 32, k0 = blockIdx.y * 32;
  int tx = threadIdx.x, ty = threadIdx.y;
  for (int i = 0; i < 4; ++i) {
    int k = k0 + ty + i * 8, n = n0 + tx;
    tile[ty + i * 8][tx] = (k < K && n < N) ? W[(size_t)k * N + n] : 0.f;
  }
  __syncthreads();
  for (int i = 0; i < 4; ++i) {
    int n = n0 + ty + i * 8, k = k0 + tx;
    WT[(size_t)n * KApad + k] = f2b(tile[tx][ty + i * 8]);
  }
}

// ---------------- conditioning ----------------
__global__ void cond1(const int* __restrict__ ts, const float* __restrict__ Wt1,
                      const float* __restrict__ bt1, float* __restrict__ t1) {
  __shared__ float pe[512];
  int b = blockIdx.x, tid = threadIdx.x;
  float pos = (float)ts[b];
  int i2 = tid >> 1;
  float dv = expf(-0.0359778920780e0f * (float)i2);
  float ang = pos * dv;
  pe[tid] = (tid & 1) ? cosf(ang) : sinf(ang);
  __syncthreads();
  float acc = bt1[tid];
  for (int k = 0; k < 512; ++k) acc += pe[k] * Wt1[k * 512 + tid];
  t1[b * 512 + tid] = acc / (1.f + expf(-acc));  // silu
}

__global__ void cond2(const float* __restrict__ t1buf, const float* __restrict__ Wt2,
                      const float* __restrict__ bt2, const float* __restrict__ enc,
                      const float* __restrict__ Wtxt, const float* __restrict__ btxt,
                      float* __restrict__ emb) {
  __shared__ float a[512], m[512];
  int b = blockIdx.x, tid = threadIdx.x;
  a[tid] = t1buf[b * 512 + tid];
  float s = 0.f;
  for (int j = 0; j < 20; ++j) s += enc[((size_t)(b * 20 + j)) * 512 + tid];
  m[tid] = s * 0.05f;
  __syncthreads();
  float acc = bt2[tid] + btxt[tid];
  for (int k = 0; k < 512; ++k) acc += a[k] * Wt2[k * 512 + tid] + m[k] * Wtxt[k * 512 + tid];
  emb[b * 512 + tid] = acc;
}

// ---------------- rope table: [512][32] float2(cos,sin) ----------------
__global__ void rope_tab(float2* __restrict__ rt) {
  int idx = blockIdx.x * 256 + threadIdx.x;  // 16384
  int t = idx >> 5, i = idx & 31;
  float ang = (float)t * __expf(-0.28782313662f * (float)i);
  float sn, cn;
  sincosf(ang, &sn, &cn);
  rt[idx] = make_float2(cn, sn);
}

// ---------------- x fp32 -> bf16 with K-pad 150->192 ----------------
__global__ void xconv(const float* __restrict__ x, u16* __restrict__ xb) {
  int idx = blockIdx.x * 256 + threadIdx.x;  // 16384*192
  int mrow = idx / 192, kk = idx - mrow * 192;
  float v = (kk < 150) ? x[(size_t)mrow * 150 + kk] : 0.f;
  xb[idx] = f2b(v);
}

// ---------------- LayerNorm: one row per wave, shuffle-only ----------------
__global__ __launch_bounds__(256) void ln_kernel(const float* __restrict__ h,
                                                 const float* __restrict__ g,
                                                 const float* __restrict__ be,
                                                 u16* __restrict__ y) {
  int w = threadIdx.x >> 6, lane = threadIdx.x & 63;
  int row = blockIdx.x * 4 + w;
  const float* hr = h + (size_t)row * 512 + lane * 8;
  float4 a = ((const float4*)hr)[0], b4 = ((const float4*)hr)[1];
  float s = a.x + a.y + a.z + a.w + b4.x + b4.y + b4.z + b4.w;
  float s2 = a.x * a.x + a.y * a.y + a.z * a.z + a.w * a.w +
             b4.x * b4.x + b4.y * b4.y + b4.z * b4.z + b4.w * b4.w;
#pragma unroll
  for (int o = 32; o; o >>= 1) {
    s += __shfl_xor(s, o, 64);
    s2 += __shfl_xor(s2, o, 64);
  }
  float mean = s * (1.f / 512.f);
  float var = s2 * (1.f / 512.f) - mean * mean;
  float rs = rsqrtf(var + 1e-5f);
  const float4* gp = (const float4*)(g + lane * 8);
  const float4* bp = (const float4*)(be + lane * 8);
  float4 g0 = gp[0], g1 = gp[1], be0 = bp[0], be1 = bp[1];
  ushort4 o0, o1;
  o0.x = f2b((a.x - mean) * rs * g0.x + be0.x);
  o0.y = f2b((a.y - mean) * rs * g0.y + be0.y);
  o0.z = f2b((a.z - mean) * rs * g0.z + be0.z);
  o0.w = f2b((a.w - mean) * rs * g0.w + be0.w);
  o1.x = f2b((b4.x - mean) * rs * g1.x + be1.x);
  o1.y = f2b((b4.y - mean) * rs * g1.y + be1.y);
  o1.z = f2b((b4.z - mean) * rs * g1.z + be1.z);
  o1.w = f2b((b4.w - mean) * rs * g1.w + be1.w);
  ushort4* yp = (ushort4*)(y + (size_t)row * 512 + lane * 8);
  yp[0] = o0;
  yp[1] = o1;
}

// ---------------- flash attention v2, MFMA bf16 ----------------
// grid (8 qtiles, 8 heads, 32 batch), 256 threads = 4 waves; wave w owns q-rows w*16..+15.
// qk layout: [b*512+t][1024] (Q cols 0..511 pre-scaled+rope'd, K cols 512..1023 rope'd).
// LDS: Qs 8K + KVs 16K (K then V^T) + Ps 16K = 40 KB -> 4 blocks/CU.
__global__ __launch_bounds__(256) void attn_mfma2(const u16* __restrict__ qk,
                                                  const u16* __restrict__ vt,
                                                  u16* __restrict__ o) {
  __shared__ u16 Qs[64 * 64];
  __shared__ u16 KVs[128 * 64];
  __shared__ u16 Ps[64 * 128];
  const int tid = threadIdx.x;
  const int qt = blockIdx.x, h = blockIdx.y, b = blockIdx.z;
  const int lane = tid & 63, w = tid >> 6;
  const int q = lane >> 4, c16 = lane & 15;

  // stage Q tile 64x64 (async)
  const size_t qbase = (size_t)(b * 512 + qt * 64) * 1024 + h * 64;
  {
    int row0 = tid >> 3, cs = tid & 7;
#pragma unroll
    for (int rep = 0; rep < 2; ++rep) {
      int r2 = rep * 32 + row0;
      int g = cs ^ (r2 & 7);
      gl_lds16(qk + qbase + (size_t)r2 * 1024 + g * 8, Qs + rep * 2048 + tid * 8);
    }
  }

  f32x4 o_acc[4];
  float m_st[4], l_st[4];
#pragma unroll
  for (int jd = 0; jd < 4; ++jd) o_acc[jd] = (f32x4){0.f, 0.f, 0.f, 0.f};
#pragma unroll
  for (int r = 0; r < 4; ++r) { m_st[r] = -1e30f; l_st[r] = 0.f; }

  const size_t kbase = (size_t)b * 512 * 1024 + 512 + h * 64;
  const size_t vtbase = ((size_t)(b * 8 + h) * 64) * 512;

  for (int kt = 0; kt < 4; ++kt) {
    if (kt) __syncthreads();  // prior PV reads of KVs/Ps done
    // stage K tile 128x64 (async)
    {
      int row0 = tid >> 3, cs = tid & 7;
#pragma unroll
      for (int rep = 0; rep < 4; ++rep) {
        int r2 = rep * 32 + row0;
        int g = cs ^ (r2 & 7);
        gl_lds16(qk + kbase + (size_t)(kt * 128 + r2) * 1024 + g * 8,
                 KVs + rep * 2048 + tid * 8);
      }
    }
    __syncthreads();  // K (and Q) visible

    // S = Q K^T  (1 m-tile x 8 n-tiles, K=64 -> 2 steps)
    f32x4 s_acc[8];
#pragma unroll
    for (int j = 0; j < 8; ++j) s_acc[j] = (f32x4){0.f, 0.f, 0.f, 0.f};
#pragma unroll
    for (int ka = 0; ka < 2; ++ka) {
      bf16x8 af, bf[8];
      {
        int row = w * 16 + c16;
        af = *(const bf16x8*)(Qs + row * 64 + (((ka * 4 + q) ^ (row & 7)) * 8));
      }
#pragma unroll
      for (int j = 0; j < 8; ++j) {
        int row = j * 16 + c16;
        bf[j] = *(const bf16x8*)(KVs + row * 64 + (((ka * 4 + q) ^ (row & 7)) * 8));
      }
#pragma unroll
      for (int j = 0; j < 8; ++j)
        s_acc[j] = __builtin_amdgcn_mfma_f32_16x16x32_bf16(af, bf[j], s_acc[j], 0, 0, 0);
    }
    __syncthreads();  // K reads done -> KVs reusable for V

    // stage V^T tile 64x128 (async); per rep = 256 lanes x 16B = 2048 u16
    {
      int vr0 = tid >> 4, cc = tid & 15;
#pragma unroll
      for (int rep = 0; rep < 4; ++rep) {
        int row = rep * 16 + vr0;
        int g2 = cc ^ (row & 15);
        gl_lds16(vt + vtbase + (size_t)row * 512 + kt * 128 + g2 * 8,
                 KVs + rep * 2048 + tid * 8);
      }
    }

    // online softmax in registers (scores pre-scaled via Q)
#pragma unroll
    for (int r = 0; r < 4; ++r) {
      float mx = s_acc[0][r];
#pragma unroll
      for (int j = 1; j < 8; ++j) mx = fmaxf(mx, s_acc[j][r]);
      mx = fmaxf(mx, __shfl_xor(mx, 1, 64));
      mx = fmaxf(mx, __shfl_xor(mx, 2, 64));
      mx = fmaxf(mx, __shfl_xor(mx, 4, 64));
      mx = fmaxf(mx, __shfl_xor(mx, 8, 64));
      float mn = fmaxf(m_st[r], mx);
      float al = __expf(m_st[r] - mn);
      m_st[r] = mn;
      float sum = 0.f;
#pragma unroll
      for (int j = 0; j < 8; ++j) {
        float p = __expf(s_acc[j][r] - mn);
        s_acc[j][r] = p;
        sum += p;
      }
      sum += __shfl_xor(sum, 1, 64);
      sum += __shfl_xor(sum, 2, 64);
      sum += __shfl_xor(sum, 4, 64);
      sum += __shfl_xor(sum, 8, 64);
      l_st[r] = l_st[r] * al + sum;
#pragma unroll
      for (int jd = 0; jd < 4; ++jd) o_acc[jd][r] *= al;
    }

    // write P (bf16, swizzled A-layout source)
#pragma unroll
    for (int j = 0; j < 8; ++j)
#pragma unroll
      for (int r = 0; r < 4; ++r) {
        int prow = w * 16 + q * 4 + r;
        int col = j * 16 + c16;
        int cp = col >> 3;
        Ps[prow * 128 + ((cp ^ (prow & 15)) * 8) + (col & 7)] = f2b(s_acc[j][r]);
      }
    __syncthreads();  // P written, V visible

    // O += P V  (128 keys -> 4 steps)
#pragma unroll
    for (int s = 0; s < 4; ++s) {
      bf16x8 af, bv[4];
      {
        int row = w * 16 + c16;
        af = *(const bf16x8*)(Ps + row * 128 + (((s * 4 + q) ^ (row & 15)) * 8));
      }
#pragma unroll
      for (int jd = 0; jd < 4; ++jd) {
        int row = jd * 16 + c16;
        bv[jd] = *(const bf16x8*)(KVs + row * 128 + (((s * 4 + q) ^ (row & 15)) * 8));
      }
#pragma unroll
      for (int jd = 0; jd < 4; ++jd)
        o_acc[jd] = __builtin_amdgcn_mfma_f32_16x16x32_bf16(af, bv[jd], o_acc[jd], 0, 0, 0);
    }
  }

  // epilogue: normalize and store
#pragma unroll
  for (int r = 0; r < 4; ++r) {
    float inv = 1.f / l_st[r];
    int trow = qt * 64 + w * 16 + q * 4 + r;
#pragma unroll
    for (int jd = 0; jd < 4; ++jd)
      o[(size_t)(b * 512 + trow) * 512 + h * 64 + jd * 16 + c16] = f2b(o_acc[jd][r] * inv);
  }
}

// ---------------- bf16 MFMA GEMM, 128x128 tile, XCD-swizzled flat grid ------
// grid = nx * 128 blocks (1-D). nx = number of 128-col N-tiles.
// Swizzle: the nx blocks sharing an M-band get the same (bid & 7) residue ->
// same XCD under round-robin, so the A-band is fetched into one XCD's L2 once.
// MODE 0: fp32 out = acc + bias + emb[row/512]
// MODE 2: fp32 out = aux(h) + acc + bias
// MODE 3: bf16 out = gelu(acc + bias)  (tanh approx)
// MODE 4: fp32 out[row*150+col] = acc + bias, col<150
// MODE 5: qkv fused rope/V^T (aux = rope table, aux2 = V^T buffer)
// MODE 6: MODE 2 + bf16 copy into aux2
template <int MODE>
__global__ __launch_bounds__(256) void gemm_bf16(
    const u16* __restrict__ A, const u16* __restrict__ BT,
    const float* __restrict__ bias, const float* aux, void* aux2, void* Cout,
    int KA, int ldc, int nx) {
  __shared__ u16 As[128 * 64];
  __shared__ u16 Bs[128 * 64];
  const int tid = threadIdx.x;
  int bid = blockIdx.x;
  int rr = bid & 7, gg = bid >> 3;
  int xN = gg % nx, yM = rr + 8 * (gg / nx);
  const int tileN = xN * 128;
  const int tileM = yM * 128;
  const int lane = tid & 63, w = tid >> 6;
  const int mw = (w >> 1) * 64, nw = (w & 1) * 64;
  const int q = lane >> 4, c16 = lane & 15;

  f32x4 acc[4][4];
#pragma unroll
  for (int i = 0; i < 4; ++i)
#pragma unroll
    for (int j = 0; j < 4; ++j) acc[i][j] = (f32x4){0.f, 0.f, 0.f, 0.f};

  const int rowA0 = tid >> 3;  // 0..31
  const int cs = tid & 7;
  const int KT = KA >> 6;
  for (int kt = 0; kt < KT; ++kt) {
    __syncthreads();
#pragma unroll
    for (int rep = 0; rep < 4; ++rep) {
      int row = rep * 32 + rowA0;
      int g = cs ^ (row & 7);
      gl_lds16(A + (size_t)(tileM + row) * KA + kt * 64 + g * 8,
               (u16*)((char*)As + rep * 4096 + tid * 16));
    }
#pragma unroll
    for (int rep = 0; rep < 4; ++rep) {
      int row = rep * 32 + rowA0;
      int g = cs ^ (row & 7);
      gl_lds16(BT + (size_t)(tileN + row) * KA + kt * 64 + g * 8,
               (u16*)((char*)Bs + rep * 4096 + tid * 16));
    }
    __syncthreads();
#pragma unroll
    for (int ks = 0; ks < 2; ++ks) {
      bf16x8 af[4], bfr[4];
#pragma unroll
      for (int i = 0; i < 4; ++i) {
        int m = mw + i * 16 + c16;
        int ca = (ks * 4 + q) ^ (m & 7);
        af[i] = *(const bf16x8*)((const char*)As + m * 128 + ca * 16);
        int n = nw + i * 16 + c16;
        int cb = (ks * 4 + q) ^ (n & 7);
        bfr[i] = *(const bf16x8*)((const char*)Bs + n * 128 + cb * 16);
      }
#pragma unroll
      for (int i = 0; i < 4; ++i)
#pragma unroll
        for (int j = 0; j < 4; ++j)
          acc[i][j] = __builtin_amdgcn_mfma_f32_16x16x32_bf16(af[i], bfr[j], acc[i][j], 0, 0, 0);
    }
  }

  if (MODE == 5) {
    // fused qkv epilogue: rope on Q (scaled) and K; transpose-store V.
    const float2* rt = (const float2*)aux;
    u16* qk = (u16*)Cout;
    u16* vtp = (u16*)aux2;
#pragma unroll
    for (int i = 0; i < 4; ++i) {
      int row = tileM + mw + i * 16 + q * 4;
      int bb = row >> 9, t0 = row & 511;
#pragma unroll
      for (int jp = 0; jp < 2; ++jp) {
        int colA = tileN + nw + jp * 16 + c16;
        if (colA < 1024) {
          int colB = colA + 32;
          int d31 = colA & 31;
          float scl = (colA < 512) ? 0.125f : 1.f;
          float bA = bias[colA], bB = bias[colB];
#pragma unroll
          for (int r = 0; r < 4; ++r) {
            float2 cs2 = rt[(t0 + r) * 32 + d31];
            float x1 = acc[i][jp][r] + bA;
            float x2 = acc[i][jp + 2][r] + bB;
            size_t rbase = (size_t)(row + r) * 1024;
            qk[rbase + colA] = f2b((x1 * cs2.x - x2 * cs2.y) * scl);
            qk[rbase + colB] = f2b((x2 * cs2.x + x1 * cs2.y) * scl);
          }
        } else {
#pragma unroll
          for (int jj = jp; jj < 4; jj += 2) {
            int col = tileN + nw + jj * 16 + c16;
            int hh = (col - 1024) >> 6, d = col & 63;
            float bv2 = bias[col];
            ushort4 pk;
            pk.x = f2b(acc[i][jj][0] + bv2);
            pk.y = f2b(acc[i][jj][1] + bv2);
            pk.z = f2b(acc[i][jj][2] + bv2);
            pk.w = f2b(acc[i][jj][3] + bv2);
            *(ushort4*)(vtp + ((size_t)((bb * 8 + hh) * 64 + d)) * 512 + t0) = pk;
          }
        }
      }
    }
    return;
  }

  // generic epilogues
#pragma unroll
  for (int i = 0; i < 4; ++i) {
#pragma unroll
    for (int j = 0; j < 4; ++j) {
      int col = tileN + nw + j * 16 + c16;
      float bv = (MODE == 4) ? 0.f : bias[col];
#pragma unroll
      for (int r = 0; r < 4; ++r) {
        int row = tileM + mw + i * 16 + q * 4 + r;
        float v = acc[i][j][r] + bv;
        if (MODE == 0) {
          ((float*)Cout)[(size_t)row * ldc + col] = v + aux[(row >> 9) * 512 + col];
        } else if (MODE == 2) {
          size_t idx = (size_t)row * ldc + col;
          ((float*)Cout)[idx] = aux[idx] + v;
        } else if (MODE == 3) {
          // gelu, tanh approximation (max |diff vs erf| ~3e-4)
          float t = 0.79788456f * (v + 0.044715f * v * v * v);
          float e = __expf(2.f * t);
          float th = (e - 1.f) / (e + 1.f);
          ((u16*)Cout)[(size_t)row * ldc + col] = f2b(0.5f * v * (1.f + th));
        } else if (MODE == 4) {
          if (col < 150) ((float*)Cout)[(size_t)row * 150 + col] = acc[i][j][r] + bias[col];
        } else if (MODE == 6) {
          size_t idx = (size_t)row * ldc + col;
          float v2 = aux[idx] + v;
          ((float*)Cout)[idx] = v2;
          ((u16*)aux2)[idx] = f2b(v2);
        }
      }
    }
  }
}

// ---------------- launch ----------------
extern "C" void kernel_launch(void* const* d_in, const int* in_sizes, int n_in,
                              void* d_out, int out_size, void* d_ws, size_t ws_size,
                              hipStream_t stream) {
  const float* x = (const float*)d_in[0];
  const int* tsteps = (const int*)d_in[1];
  const float* enc = (const float*)d_in[2];
  const float* W_in = (const float*)d_in[3];
  const float* b_in = (const float*)d_in[4];
  const float* W_t1 = (const float*)d_in[5];
  const float* b_t1 = (const float*)d_in[6];
  const float* W_t2 = (const float*)d_in[7];
  const float* b_t2 = (const float*)d_in[8];
  const float* W_txt = (const float*)d_in[9];
  const float* b_txt = (const float*)d_in[10];
  const float* ln1_g = (const float*)d_in[11];
  const float* ln1_b = (const float*)d_in[12];
  const float* Wqkv = (const float*)d_in[13];
  const float* bqkv = (const float*)d_in[14];
  const float* Wo = (const float*)d_in[15];
  const float* bo = (const float*)d_in[16];
  const float* ln2_g = (const float*)d_in[17];
  const float* ln2_b = (const float*)d_in[18];
  const float* W1 = (const float*)d_in[19];
  const float* b1 = (const float*)d_in[20];
  const float* W2 = (const float*)d_in[21];
  const float* b2 = (const float*)d_in[22];
  const float* W_out = (const float*)d_in[23];
  const float* b_out = (const float*)d_in[24];

  char* ws = (char*)d_ws;
  u16* WT_in = (u16*)(ws + 0);              // 512*192
  u16* WT_qkv = (u16*)(ws + 196608);        // 8*1536*512
  u16* WT_o = (u16*)(ws + 12779520);        // 8*512*512
  u16* WT_1 = (u16*)(ws + 16973824);        // 8*2048*512
  u16* WT_2 = (u16*)(ws + 33751040);        // 8*512*2048
  u16* WT_out = (u16*)(ws + 50528256);      // 256*512
  u16* xb = (u16*)(ws + 50790400);          // 16384*192
  float* hf = (float*)(ws + 57081856);      // 16384*512 f32
  u16* yb = (u16*)(ws + 90636288);          // 16384*512
  u16* qkvb = (u16*)(ws + 107413504);       // 16384*1024 (Q,K rope'd); tail reused:
  float2* rtab = (float2*)(ws + 107413504 + 33554432);  // 512*32 float2 = 128 KB
  u16* ob = (u16*)(ws + 157745152);         // 16384*512
  u16* ffb = (u16*)(ws + 174522368);        // 16384*2048
  u16* hb = (u16*)(ws + 241631232);         // 16384*512 (final h bf16; idle during layers)
  u16* vtb = hb;                            // aliased: V^T [b][h][64][512], layer-loop only
  float* embf = (float*)(ws + 258408448);   // 32*512 f32
  float* t1c = (float*)(ws + 258473984);    // 32*512 f32

  dim3 tb(32, 8);
  tconv<<<dim3(16, 6, 1), tb, 0, stream>>>(W_in, WT_in, 150, 512, 192, 512);
  tconv<<<dim3(48, 16, 8), tb, 0, stream>>>(Wqkv, WT_qkv, 512, 1536, 512, 1536);
  tconv<<<dim3(16, 16, 8), tb, 0, stream>>>(Wo, WT_o, 512, 512, 512, 512);
  tconv<<<dim3(64, 16, 8), tb, 0, stream>>>(W1, WT_1, 512, 2048, 512, 2048);
  tconv<<<dim3(16, 64, 8), tb, 0, stream>>>(W2, WT_2, 2048, 512, 2048, 512);
  tconv<<<dim3(8, 16, 1), tb, 0, stream>>>(W_out, WT_out, 512, 150, 512, 256);

  cond1<<<32, 512, 0, stream>>>(tsteps, W_t1, b_t1, t1c);
  cond2<<<32, 512, 0, stream>>>(t1c, W_t2, b_t2, enc, W_txt, b_txt, embf);
  rope_tab<<<64, 256, 0, stream>>>(rtab);
  xconv<<<12288, 256, 0, stream>>>(x, xb);

  // h = x @ W_in + b_in + emb
  gemm_bf16<0><<<4 * 128, 256, 0, stream>>>(xb, WT_in, b_in, embf, nullptr, hf, 192, 512, 4);

  for (int l = 0; l < 8; ++l) {
    ln_kernel<<<4096, 256, 0, stream>>>(hf, ln1_g + l * 512, ln1_b + l * 512, yb);
    gemm_bf16<5><<<12 * 128, 256, 0, stream>>>(yb, WT_qkv + (size_t)l * 1536 * 512,
                                               bqkv + l * 1536, (const float*)rtab,
                                               vtb, qkvb, 512, 1024, 12);
    attn_mfma2<<<dim3(8, 8, 32), 256, 0, stream>>>(qkvb, vtb, ob);
    gemm_bf16<2><<<4 * 128, 256, 0, stream>>>(ob, WT_o + (size_t)l * 512 * 512,
                                              bo + l * 512, hf, nullptr, hf, 512, 512, 4);
    ln_kernel<<<4096, 256, 0, stream>>>(hf, ln2_g + l * 512, ln2_b + l * 512, yb);
    gemm_bf16<3><<<16 * 128, 256, 0, stream>>>(yb, WT_1 + (size_t)l * 2048 * 512,
                                               b1 + l * 2048, nullptr, nullptr, ffb, 512, 2048, 16);
    if (l < 7) {
      gemm_bf16<2><<<4 * 128, 256, 0, stream>>>(ffb, WT_2 + (size_t)l * 512 * 2048,
                                                b2 + l * 512, hf, nullptr, hf, 2048, 512, 4);
    } else {
      gemm_bf16<6><<<4 * 128, 256, 0, stream>>>(ffb, WT_2 + (size_t)l * 512 * 2048,
                                                b2 + l * 512, hf, hb, hf, 2048, 512, 4);
    }
  }

  gemm_bf16<4><<<2 * 128, 256, 0, stream>>>(hb, WT_out, b_out, nullptr, nullptr, d_out, 512, 150, 2);
}

// Round 8
// 2435.288 us; speedup vs baseline: 1.3088x; 1.0005x over previous
//
#include <hip/hip_runtime.h>
#include <hip/hip_bf16.h>
#include <math.h>

typedef unsigned short u16;
typedef __attribute__((ext_vector_type(8))) short bf16x8;
typedef __attribute__((ext_vector_type(4))) float f32x4;

__device__ __forceinline__ u16 f2b(float x) {
  union { float f; unsigned u; } c; c.f = x;
  unsigned r = c.u + 0x7FFFu + ((c.u >> 16) & 1u);
  return (u16)(r >> 16);
}
__device__ __forceinline__ float b2f(u16 u) {
  union { unsigned u; float f; } c; c.u = ((unsigned)u) << 16;
  return c.f;
}

__device__ __forceinline__ void gl_lds16(const u16* g, u16* l) {
  __builtin_amdgcn_global_load_lds(
      (const __attribute__((address_space(1))) void*)g,
      (__attribute__((address_space(3))) void*)l, 16, 0, 0);
}

// ---------------- transpose + fp32->bf16 convert: W[K][N] -> WT[Npad][KApad] ---------
__global__ void tconv(const float* __restrict__ W, u16* __restrict__ WT,
                      int K, int N, int KApad, int Npad) {
  __shared__ float tile[32][33];
  int z = blockIdx.z;
  W += (size_t)z * K * N;
  WT += (size_t)z * Npad * KApad;
  int n0 = blockIdx.x * 32, k0 = blockIdx.y * 32;
  int tx = threadIdx.x, ty = threadIdx.y;
  for (int i = 0; i < 4; ++i) {
    int k = k0 + ty + i * 8, n = n0 + tx;
    tile[ty + i * 8][tx] = (k < K && n < N) ? W[(size_t)k * N + n] : 0.f;
  }
  __syncthreads();
  for (int i = 0; i < 4; ++i) {
    int n = n0 + ty + i * 8, k = k0 + tx;
    WT[(size_t)n * KApad + k] = f2b(tile[tx][ty + i * 8]);
  }
}

// ---------------- conditioning ----------------
__global__ void cond1(const int* __restrict__ ts, const float* __restrict__ Wt1,
                      const float* __restrict__ bt1, float* __restrict__ t1) {
  __shared__ float pe[512];
  int b = blockIdx.x, tid = threadIdx.x;
  float pos = (float)ts[b];
  int i2 = tid >> 1;
  float dv = expf(-0.0359778920780e0f * (float)i2);
  float ang = pos * dv;
  pe[tid] = (tid & 1) ? cosf(ang) : sinf(ang);
  __syncthreads();
  float acc = bt1[tid];
  for (int k = 0; k < 512; ++k) acc += pe[k] * Wt1[k * 512 + tid];
  t1[b * 512 + tid] = acc / (1.f + expf(-acc));  // silu
}

__global__ void cond2(const float* __restrict__ t1buf, const float* __restrict__ Wt2,
                      const float* __restrict__ bt2, const float* __restrict__ enc,
                      const float* __restrict__ Wtxt, const float* __restrict__ btxt,
                      float* __restrict__ emb) {
  __shared__ float a[512], m[512];
  int b = blockIdx.x, tid = threadIdx.x;
  a[tid] = t1buf[b * 512 + tid];
  float s = 0.f;
  for (int j = 0; j < 20; ++j) s += enc[((size_t)(b * 20 + j)) * 512 + tid];
  m[tid] = s * 0.05f;
  __syncthreads();
  float acc = bt2[tid] + btxt[tid];
  for (int k = 0; k < 512; ++k) acc += a[k] * Wt2[k * 512 + tid] + m[k] * Wtxt[k * 512 + tid];
  emb[b * 512 + tid] = acc;
}

// ---------------- rope table: [512][32] float2(cos,sin) ----------------
__global__ void rope_tab(float2* __restrict__ rt) {
  int idx = blockIdx.x * 256 + threadIdx.x;  // 16384
  int t = idx >> 5, i = idx & 31;
  float ang = (float)t * __expf(-0.28782313662f * (float)i);
  float sn, cn;
  sincosf(ang, &sn, &cn);
  rt[idx] = make_float2(cn, sn);
}

// ---------------- x fp32 -> bf16 with K-pad 150->192 ----------------
__global__ void xconv(const float* __restrict__ x, u16* __restrict__ xb) {
  int idx = blockIdx.x * 256 + threadIdx.x;  // 16384*192
  int mrow = idx / 192, kk = idx - mrow * 192;
  float v = (kk < 150) ? x[(size_t)mrow * 150 + kk] : 0.f;
  xb[idx] = f2b(v);
}

// ---------------- LayerNorm: one row per wave, shuffle-only ----------------
__global__ __launch_bounds__(256) void ln_kernel(const float* __restrict__ h,
                                                 const float* __restrict__ g,
                                                 const float* __restrict__ be,
                                                 u16* __restrict__ y) {
  int w = threadIdx.x >> 6, lane = threadIdx.x & 63;
  int row = blockIdx.x * 4 + w;
  const float* hr = h + (size_t)row * 512 + lane * 8;
  float4 a = ((const float4*)hr)[0], b4 = ((const float4*)hr)[1];
  float s = a.x + a.y + a.z + a.w + b4.x + b4.y + b4.z + b4.w;
  float s2 = a.x * a.x + a.y * a.y + a.z * a.z + a.w * a.w +
             b4.x * b4.x + b4.y * b4.y + b4.z * b4.z + b4.w * b4.w;
#pragma unroll
  for (int o = 32; o; o >>= 1) {
    s += __shfl_xor(s, o, 64);
    s2 += __shfl_xor(s2, o, 64);
  }
  float mean = s * (1.f / 512.f);
  float var = s2 * (1.f / 512.f) - mean * mean;
  float rs = rsqrtf(var + 1e-5f);
  const float4* gp = (const float4*)(g + lane * 8);
  const float4* bp = (const float4*)(be + lane * 8);
  float4 g0 = gp[0], g1 = gp[1], be0 = bp[0], be1 = bp[1];
  ushort4 o0, o1;
  o0.x = f2b((a.x - mean) * rs * g0.x + be0.x);
  o0.y = f2b((a.y - mean) * rs * g0.y + be0.y);
  o0.z = f2b((a.z - mean) * rs * g0.z + be0.z);
  o0.w = f2b((a.w - mean) * rs * g0.w + be0.w);
  o1.x = f2b((b4.x - mean) * rs * g1.x + be1.x);
  o1.y = f2b((b4.y - mean) * rs * g1.y + be1.y);
  o1.z = f2b((b4.z - mean) * rs * g1.z + be1.z);
  o1.w = f2b((b4.w - mean) * rs * g1.w + be1.w);
  ushort4* yp = (ushort4*)(y + (size_t)row * 512 + lane * 8);
  yp[0] = o0;
  yp[1] = o1;
}

// ---------------- flash attention v3: 2 q-tiles per block share K/V ----------------
// grid (4 qtile-pairs, 8 heads, 32 batch), 256 threads = 4 waves.
// Block handles q-rows [bx*128, bx*128+128) as two 64-row tiles A,B.
// K/V staged ONCE per kt for both tiles (half the staging traffic of v2).
// LDS: Qs 16K + KVs 16K (K then V^T) + Ps 16K = 48 KB -> 3 blocks/CU.
__global__ __launch_bounds__(256) void attn_mfma3(const u16* __restrict__ qk,
                                                  const u16* __restrict__ vt,
                                                  u16* __restrict__ o) {
  __shared__ u16 Qs[128 * 64];
  __shared__ u16 KVs[128 * 64];
  __shared__ u16 Ps[64 * 128];
  const int tid = threadIdx.x;
  const int bx = blockIdx.x, h = blockIdx.y, b = blockIdx.z;
  const int lane = tid & 63, w = tid >> 6;
  const int q = lane >> 4, c16 = lane & 15;

  // stage both Q tiles (128 contiguous rows, async)
  const size_t qbase = (size_t)(b * 512 + bx * 128) * 1024 + h * 64;
  {
    int row0 = tid >> 3, cs = tid & 7;
#pragma unroll
    for (int rep = 0; rep < 4; ++rep) {
      int r2 = rep * 32 + row0;
      int g = cs ^ (r2 & 7);
      gl_lds16(qk + qbase + (size_t)r2 * 1024 + g * 8, Qs + rep * 2048 + tid * 8);
    }
  }

  f32x4 oA[4], oB[4];
  float mA[4], lA[4], mB[4], lB[4];
#pragma unroll
  for (int jd = 0; jd < 4; ++jd) {
    oA[jd] = (f32x4){0.f, 0.f, 0.f, 0.f};
    oB[jd] = (f32x4){0.f, 0.f, 0.f, 0.f};
  }
#pragma unroll
  for (int r = 0; r < 4; ++r) { mA[r] = -1e30f; lA[r] = 0.f; mB[r] = -1e30f; lB[r] = 0.f; }

  const size_t kbase = (size_t)b * 512 * 1024 + 512 + h * 64;
  const size_t vtbase = ((size_t)(b * 8 + h) * 64) * 512;

  for (int kt = 0; kt < 4; ++kt) {
    if (kt) __syncthreads();  // prior PV_b done with KVs(V); Ps free
    // stage K tile 128x64 (async)
    {
      int row0 = tid >> 3, cs = tid & 7;
#pragma unroll
      for (int rep = 0; rep < 4; ++rep) {
        int r2 = rep * 32 + row0;
        int g = cs ^ (r2 & 7);
        gl_lds16(qk + kbase + (size_t)(kt * 128 + r2) * 1024 + g * 8,
                 KVs + rep * 2048 + tid * 8);
      }
    }
    __syncthreads();  // K (and Q) visible

    f32x4 s_acc[8];

    // ---- S_A = Q_A K^T ----
#pragma unroll
    for (int j = 0; j < 8; ++j) s_acc[j] = (f32x4){0.f, 0.f, 0.f, 0.f};
#pragma unroll
    for (int ka = 0; ka < 2; ++ka) {
      bf16x8 af, bf[8];
      {
        int row = w * 16 + c16;
        af = *(const bf16x8*)(Qs + row * 64 + (((ka * 4 + q) ^ (row & 7)) * 8));
      }
#pragma unroll
      for (int j = 0; j < 8; ++j) {
        int row = j * 16 + c16;
        bf[j] = *(const bf16x8*)(KVs + row * 64 + (((ka * 4 + q) ^ (row & 7)) * 8));
      }
#pragma unroll
      for (int j = 0; j < 8; ++j)
        s_acc[j] = __builtin_amdgcn_mfma_f32_16x16x32_bf16(af, bf[j], s_acc[j], 0, 0, 0);
    }
    // softmax_A (regs) + write P_A (own-wave rows of Ps)
#pragma unroll
    for (int r = 0; r < 4; ++r) {
      float mx = s_acc[0][r];
#pragma unroll
      for (int j = 1; j < 8; ++j) mx = fmaxf(mx, s_acc[j][r]);
      mx = fmaxf(mx, __shfl_xor(mx, 1, 64));
      mx = fmaxf(mx, __shfl_xor(mx, 2, 64));
      mx = fmaxf(mx, __shfl_xor(mx, 4, 64));
      mx = fmaxf(mx, __shfl_xor(mx, 8, 64));
      float mn = fmaxf(mA[r], mx);
      float al = __expf(mA[r] - mn);
      mA[r] = mn;
      float sum = 0.f;
#pragma unroll
      for (int j = 0; j < 8; ++j) {
        float p = __expf(s_acc[j][r] - mn);
        s_acc[j][r] = p;
        sum += p;
      }
      sum += __shfl_xor(sum, 1, 64);
      sum += __shfl_xor(sum, 2, 64);
      sum += __shfl_xor(sum, 4, 64);
      sum += __shfl_xor(sum, 8, 64);
      lA[r] = lA[r] * al + sum;
#pragma unroll
      for (int jd = 0; jd < 4; ++jd) oA[jd][r] *= al;
    }
#pragma unroll
    for (int j = 0; j < 8; ++j)
#pragma unroll
      for (int r = 0; r < 4; ++r) {
        int prow = w * 16 + q * 4 + r;
        int col = j * 16 + c16;
        Ps[prow * 128 + (((col >> 3) ^ (prow & 15)) * 8) + (col & 7)] = f2b(s_acc[j][r]);
      }

    // ---- S_B = Q_B K^T (K still resident) ----
#pragma unroll
    for (int j = 0; j < 8; ++j) s_acc[j] = (f32x4){0.f, 0.f, 0.f, 0.f};
#pragma unroll
    for (int ka = 0; ka < 2; ++ka) {
      bf16x8 af, bf[8];
      {
        int row = 64 + w * 16 + c16;
        af = *(const bf16x8*)(Qs + row * 64 + (((ka * 4 + q) ^ (row & 7)) * 8));
      }
#pragma unroll
      for (int j = 0; j < 8; ++j) {
        int row = j * 16 + c16;
        bf[j] = *(const bf16x8*)(KVs + row * 64 + (((ka * 4 + q) ^ (row & 7)) * 8));
      }
#pragma unroll
      for (int j = 0; j < 8; ++j)
        s_acc[j] = __builtin_amdgcn_mfma_f32_16x16x32_bf16(af, bf[j], s_acc[j], 0, 0, 0);
    }
    __syncthreads();  // all K reads done; P_A written

    // stage V^T tile 64x128 (async) into KVs; overlaps softmax_B
    {
      int vr0 = tid >> 4, cc = tid & 15;
#pragma unroll
      for (int rep = 0; rep < 4; ++rep) {
        int row = rep * 16 + vr0;
        int g2 = cc ^ (row & 15);
        gl_lds16(vt + vtbase + (size_t)row * 512 + kt * 128 + g2 * 8,
                 KVs + rep * 2048 + tid * 8);
      }
    }

    // softmax_B (regs only)
#pragma unroll
    for (int r = 0; r < 4; ++r) {
      float mx = s_acc[0][r];
#pragma unroll
      for (int j = 1; j < 8; ++j) mx = fmaxf(mx, s_acc[j][r]);
      mx = fmaxf(mx, __shfl_xor(mx, 1, 64));
      mx = fmaxf(mx, __shfl_xor(mx, 2, 64));
      mx = fmaxf(mx, __shfl_xor(mx, 4, 64));
      mx = fmaxf(mx, __shfl_xor(mx, 8, 64));
      float mn = fmaxf(mB[r], mx);
      float al = __expf(mB[r] - mn);
      mB[r] = mn;
      float sum = 0.f;
#pragma unroll
      for (int j = 0; j < 8; ++j) {
        float p = __expf(s_acc[j][r] - mn);
        s_acc[j][r] = p;
        sum += p;
      }
      sum += __shfl_xor(sum, 1, 64);
      sum += __shfl_xor(sum, 2, 64);
      sum += __shfl_xor(sum, 4, 64);
      sum += __shfl_xor(sum, 8, 64);
      lB[r] = lB[r] * al + sum;
#pragma unroll
      for (int jd = 0; jd < 4; ++jd) oB[jd][r] *= al;
    }
    __syncthreads();  // V visible

    // ---- O_A += P_A V ----
#pragma unroll
    for (int s = 0; s < 4; ++s) {
      bf16x8 af, bv[4];
      {
        int row = w * 16 + c16;
        af = *(const bf16x8*)(Ps + row * 128 + (((s * 4 + q) ^ (row & 15)) * 8));
      }
#pragma unroll
      for (int jd = 0; jd < 4; ++jd) {
        int row = jd * 16 + c16;
        bv[jd] = *(const bf16x8*)(KVs + row * 128 + (((s * 4 + q) ^ (row & 15)) * 8));
      }
#pragma unroll
      for (int jd = 0; jd < 4; ++jd)
        oA[jd] = __builtin_amdgcn_mfma_f32_16x16x32_bf16(af, bv[jd], oA[jd], 0, 0, 0);
    }
    __syncthreads();  // P_A reads done (conservative; Ps rows are wave-private)

    // write P_B
#pragma unroll
    for (int j = 0; j < 8; ++j)
#pragma unroll
      for (int r = 0; r < 4; ++r) {
        int prow = w * 16 + q * 4 + r;
        int col = j * 16 + c16;
        Ps[prow * 128 + (((col >> 3) ^ (prow & 15)) * 8) + (col & 7)] = f2b(s_acc[j][r]);
      }
    __syncthreads();  // P_B written (conservative)

    // ---- O_B += P_B V ----
#pragma unroll
    for (int s = 0; s < 4; ++s) {
      bf16x8 af, bv[4];
      {
        int row = w * 16 + c16;
        af = *(const bf16x8*)(Ps + row * 128 + (((s * 4 + q) ^ (row & 15)) * 8));
      }
#pragma unroll
      for (int jd = 0; jd < 4; ++jd) {
        int row = jd * 16 + c16;
        bv[jd] = *(const bf16x8*)(KVs + row * 128 + (((s * 4 + q) ^ (row & 15)) * 8));
      }
#pragma unroll
      for (int jd = 0; jd < 4; ++jd)
        oB[jd] = __builtin_amdgcn_mfma_f32_16x16x32_bf16(af, bv[jd], oB[jd], 0, 0, 0);
    }
  }

  // epilogue: normalize and store both tiles
#pragma unroll
  for (int r = 0; r < 4; ++r) {
    float invA = 1.f / lA[r], invB = 1.f / lB[r];
    int trowA = bx * 128 + w * 16 + q * 4 + r;
    int trowB = trowA + 64;
#pragma unroll
    for (int jd = 0; jd < 4; ++jd) {
      o[(size_t)(b * 512 + trowA) * 512 + h * 64 + jd * 16 + c16] = f2b(oA[jd][r] * invA);
      o[(size_t)(b * 512 + trowB) * 512 + h * 64 + jd * 16 + c16] = f2b(oB[jd][r] * invB);
    }
  }
}

// ---------------- bf16 MFMA GEMM, 128x128 tile, XCD-swizzled flat grid ------
// grid = nx * 128 blocks (1-D). nx = number of 128-col N-tiles.
// Swizzle: the nx blocks sharing an M-band get the same (bid & 7) residue ->
// same XCD under round-robin, so the A-band is fetched into one XCD's L2 once.
// MODE 0: fp32 out = acc + bias + emb[row/512]
// MODE 2: fp32 out = aux(h) + acc + bias
// MODE 3: bf16 out = gelu(acc + bias)  (tanh approx, sigmoid form)
// MODE 4: fp32 out[row*150+col] = acc + bias, col<150
// MODE 5: qkv fused rope/V^T (aux = rope table, aux2 = V^T buffer)
// MODE 6: MODE 2 + bf16 copy into aux2
template <int MODE>
__global__ __launch_bounds__(256) void gemm_bf16(
    const u16* __restrict__ A, const u16* __restrict__ BT,
    const float* __restrict__ bias, const float* aux, void* aux2, void* Cout,
    int KA, int ldc, int nx) {
  __shared__ u16 As[128 * 64];
  __shared__ u16 Bs[128 * 64];
  const int tid = threadIdx.x;
  int bid = blockIdx.x;
  int rr = bid & 7, gg = bid >> 3;
  int xN = gg % nx, yM = rr + 8 * (gg / nx);
  const int tileN = xN * 128;
  const int tileM = yM * 128;
  const int lane = tid & 63, w = tid >> 6;
  const int mw = (w >> 1) * 64, nw = (w & 1) * 64;
  const int q = lane >> 4, c16 = lane & 15;

  f32x4 acc[4][4];
#pragma unroll
  for (int i = 0; i < 4; ++i)
#pragma unroll
    for (int j = 0; j < 4; ++j) acc[i][j] = (f32x4){0.f, 0.f, 0.f, 0.f};

  const int rowA0 = tid >> 3;  // 0..31
  const int cs = tid & 7;
  const int KT = KA >> 6;
  for (int kt = 0; kt < KT; ++kt) {
    __syncthreads();
#pragma unroll
    for (int rep = 0; rep < 4; ++rep) {
      int row = rep * 32 + rowA0;
      int g = cs ^ (row & 7);
      gl_lds16(A + (size_t)(tileM + row) * KA + kt * 64 + g * 8,
               (u16*)((char*)As + rep * 4096 + tid * 16));
    }
#pragma unroll
    for (int rep = 0; rep < 4; ++rep) {
      int row = rep * 32 + rowA0;
      int g = cs ^ (row & 7);
      gl_lds16(BT + (size_t)(tileN + row) * KA + kt * 64 + g * 8,
               (u16*)((char*)Bs + rep * 4096 + tid * 16));
    }
    __syncthreads();
#pragma unroll
    for (int ks = 0; ks < 2; ++ks) {
      bf16x8 af[4], bfr[4];
#pragma unroll
      for (int i = 0; i < 4; ++i) {
        int m = mw + i * 16 + c16;
        int ca = (ks * 4 + q) ^ (m & 7);
        af[i] = *(const bf16x8*)((const char*)As + m * 128 + ca * 16);
        int n = nw + i * 16 + c16;
        int cb = (ks * 4 + q) ^ (n & 7);
        bfr[i] = *(const bf16x8*)((const char*)Bs + n * 128 + cb * 16);
      }
#pragma unroll
      for (int i = 0; i < 4; ++i)
#pragma unroll
        for (int j = 0; j < 4; ++j)
          acc[i][j] = __builtin_amdgcn_mfma_f32_16x16x32_bf16(af[i], bfr[j], acc[i][j], 0, 0, 0);
    }
  }

  if (MODE == 5) {
    // fused qkv epilogue: rope on Q (scaled) and K; transpose-store V.
    const float2* rt = (const float2*)aux;
    u16* qk = (u16*)Cout;
    u16* vtp = (u16*)aux2;
#pragma unroll
    for (int i = 0; i < 4; ++i) {
      int row = tileM + mw + i * 16 + q * 4;
      int bb = row >> 9, t0 = row & 511;
#pragma unroll
      for (int jp = 0; jp < 2; ++jp) {
        int colA = tileN + nw + jp * 16 + c16;
        if (colA < 1024) {
          int colB = colA + 32;
          int d31 = colA & 31;
          float scl = (colA < 512) ? 0.125f : 1.f;
          float bA = bias[colA], bB = bias[colB];
#pragma unroll
          for (int r = 0; r < 4; ++r) {
            float2 cs2 = rt[(t0 + r) * 32 + d31];
            float x1 = acc[i][jp][r] + bA;
            float x2 = acc[i][jp + 2][r] + bB;
            size_t rbase = (size_t)(row + r) * 1024;
            qk[rbase + colA] = f2b((x1 * cs2.x - x2 * cs2.y) * scl);
            qk[rbase + colB] = f2b((x2 * cs2.x + x1 * cs2.y) * scl);
          }
        } else {
#pragma unroll
          for (int jj = jp; jj < 4; jj += 2) {
            int col = tileN + nw + jj * 16 + c16;
            int hh = (col - 1024) >> 6, d = col & 63;
            float bv2 = bias[col];
            ushort4 pk;
            pk.x = f2b(acc[i][jj][0] + bv2);
            pk.y = f2b(acc[i][jj][1] + bv2);
            pk.z = f2b(acc[i][jj][2] + bv2);
            pk.w = f2b(acc[i][jj][3] + bv2);
            *(ushort4*)(vtp + ((size_t)((bb * 8 + hh) * 64 + d)) * 512 + t0) = pk;
          }
        }
      }
    }
    return;
  }

  // generic epilogues
#pragma unroll
  for (int i = 0; i < 4; ++i) {
#pragma unroll
    for (int j = 0; j < 4; ++j) {
      int col = tileN + nw + j * 16 + c16;
      float bv = (MODE == 4) ? 0.f : bias[col];
#pragma unroll
      for (int r = 0; r < 4; ++r) {
        int row = tileM + mw + i * 16 + q * 4 + r;
        float v = acc[i][j][r] + bv;
        if (MODE == 0) {
          ((float*)Cout)[(size_t)row * ldc + col] = v + aux[(row >> 9) * 512 + col];
        } else if (MODE == 2) {
          size_t idx = (size_t)row * ldc + col;
          ((float*)Cout)[idx] = aux[idx] + v;
        } else if (MODE == 3) {
          // gelu tanh-approx in sigmoid form: v * sigma(1.5957691*v*(1+0.044715 v^2))
          float u = v * v;
          float p = __builtin_fmaf(0.044715f, u, 1.0f);
          float t2 = v * p;
          float e = __expf(-1.59576912f * t2);
          float r2 = __builtin_amdgcn_rcpf(1.0f + e);
          ((u16*)Cout)[(size_t)row * ldc + col] = f2b(v * r2);
        } else if (MODE == 4) {
          if (col < 150) ((float*)Cout)[(size_t)row * 150 + col] = acc[i][j][r] + bias[col];
        } else if (MODE == 6) {
          size_t idx = (size_t)row * ldc + col;
          float v2 = aux[idx] + v;
          ((float*)Cout)[idx] = v2;
          ((u16*)aux2)[idx] = f2b(v2);
        }
      }
    }
  }
}

// ---------------- launch ----------------
extern "C" void kernel_launch(void* const* d_in, const int* in_sizes, int n_in,
                              void* d_out, int out_size, void* d_ws, size_t ws_size,
                              hipStream_t stream) {
  const float* x = (const float*)d_in[0];
  const int* tsteps = (const int*)d_in[1];
  const float* enc = (const float*)d_in[2];
  const float* W_in = (const float*)d_in[3];
  const float* b_in = (const float*)d_in[4];
  const float* W_t1 = (const float*)d_in[5];
  const float* b_t1 = (const float*)d_in[6];
  const float* W_t2 = (const float*)d_in[7];
  const float* b_t2 = (const float*)d_in[8];
  const float* W_txt = (const float*)d_in[9];
  const float* b_txt = (const float*)d_in[10];
  const float* ln1_g = (const float*)d_in[11];
  const float* ln1_b = (const float*)d_in[12];
  const float* Wqkv = (const float*)d_in[13];
  const float* bqkv = (const float*)d_in[14];
  const float* Wo = (const float*)d_in[15];
  const float* bo = (const float*)d_in[16];
  const float* ln2_g = (const float*)d_in[17];
  const float* ln2_b = (const float*)d_in[18];
  const float* W1 = (const float*)d_in[19];
  const float* b1 = (const float*)d_in[20];
  const float* W2 = (const float*)d_in[21];
  const float* b2 = (const float*)d_in[22];
  const float* W_out = (const float*)d_in[23];
  const float* b_out = (const float*)d_in[24];

  char* ws = (char*)d_ws;
  u16* WT_in = (u16*)(ws + 0);              // 512*192
  u16* WT_qkv = (u16*)(ws + 196608);        // 8*1536*512
  u16* WT_o = (u16*)(ws + 12779520);        // 8*512*512
  u16* WT_1 = (u16*)(ws + 16973824);        // 8*2048*512
  u16* WT_2 = (u16*)(ws + 33751040);        // 8*512*2048
  u16* WT_out = (u16*)(ws + 50528256);      // 256*512
  u16* xb = (u16*)(ws + 50790400);          // 16384*192
  float* hf = (float*)(ws + 57081856);      // 16384*512 f32
  u16* yb = (u16*)(ws + 90636288);          // 16384*512
  u16* qkvb = (u16*)(ws + 107413504);       // 16384*1024 (Q,K rope'd); tail reused:
  float2* rtab = (float2*)(ws + 107413504 + 33554432);  // 512*32 float2 = 128 KB
  u16* ob = (u16*)(ws + 157745152);         // 16384*512
  u16* ffb = (u16*)(ws + 174522368);        // 16384*2048
  u16* hb = (u16*)(ws + 241631232);         // 16384*512 (final h bf16; idle during layers)
  u16* vtb = hb;                            // aliased: V^T [b][h][64][512], layer-loop only
  float* embf = (float*)(ws + 258408448);   // 32*512 f32
  float* t1c = (float*)(ws + 258473984);    // 32*512 f32

  dim3 tb(32, 8);
  tconv<<<dim3(16, 6, 1), tb, 0, stream>>>(W_in, WT_in, 150, 512, 192, 512);
  tconv<<<dim3(48, 16, 8), tb, 0, stream>>>(Wqkv, WT_qkv, 512, 1536, 512, 1536);
  tconv<<<dim3(16, 16, 8), tb, 0, stream>>>(Wo, WT_o, 512, 512, 512, 512);
  tconv<<<dim3(64, 16, 8), tb, 0, stream>>>(W1, WT_1, 512, 2048, 512, 2048);
  tconv<<<dim3(16, 64, 8), tb, 0, stream>>>(W2, WT_2, 2048, 512, 2048, 512);
  tconv<<<dim3(8, 16, 1), tb, 0, stream>>>(W_out, WT_out, 512, 150, 512, 256);

  cond1<<<32, 512, 0, stream>>>(tsteps, W_t1, b_t1, t1c);
  cond2<<<32, 512, 0, stream>>>(t1c, W_t2, b_t2, enc, W_txt, b_txt, embf);
  rope_tab<<<64, 256, 0, stream>>>(rtab);
  xconv<<<12288, 256, 0, stream>>>(x, xb);

  // h = x @ W_in + b_in + emb
  gemm_bf16<0><<<4 * 128, 256, 0, stream>>>(xb, WT_in, b_in, embf, nullptr, hf, 192, 512, 4);

  for (int l = 0; l < 8; ++l) {
    ln_kernel<<<4096, 256, 0, stream>>>(hf, ln1_g + l * 512, ln1_b + l * 512, yb);
    gemm_bf16<5><<<12 * 128, 256, 0, stream>>>(yb, WT_qkv + (size_t)l * 1536 * 512,
                                               bqkv + l * 1536, (const float*)rtab,
                                               vtb, qkvb, 512, 1024, 12);
    attn_mfma3<<<dim3(4, 8, 32), 256, 0, stream>>>(qkvb, vtb, ob);
    gemm_bf16<2><<<4 * 128, 256, 0, stream>>>(ob, WT_o + (size_t)l * 512 * 512,
                                              bo + l * 512, hf, nullptr, hf, 512, 512, 4);
    ln_kernel<<<4096, 256, 0, stream>>>(hf, ln2_g + l * 512, ln2_b + l * 512, yb);
    gemm_bf16<3><<<16 * 128, 256, 0, stream>>>(yb, WT_1 + (size_t)l * 2048 * 512,
                                               b1 + l * 2048, nullptr, nullptr, ffb, 512, 2048, 16);
    if (l < 7) {
      gemm_bf16<2><<<4 * 128, 256, 0, stream>>>(ffb, WT_2 + (size_t)l * 512 * 2048,
                                                b2 + l * 512, hf, nullptr, hf, 2048, 512, 4);
    } else {
      gemm_bf16<6><<<4 * 128, 256, 0, stream>>>(ffb, WT_2 + (size_t)l * 512 * 2048,
                                                b2 + l * 512, hf, hb, hf, 2048, 512, 4);
    }
  }

  gemm_bf16<4><<<2 * 128, 256, 0, stream>>>(hb, WT_out, b_out, nullptr, nullptr, d_out, 512, 150, 2);
}

// Round 9
// 2257.444 us; speedup vs baseline: 1.4119x; 1.0788x over previous
//
#include <hip/hip_runtime.h>
#include <hip/hip_bf16.h>
#include <math.h>

typedef unsigned short u16;
typedef __attribute__((ext_vector_type(8))) short bf16x8;
typedef __attribute__((ext_vector_type(4))) float f32x4;

__device__ __forceinline__ u16 f2b(float x) {
  union { float f; unsigned u; } c; c.f = x;
  unsigned r = c.u + 0x7FFFu + ((c.u >> 16) & 1u);
  return (u16)(r >> 16);
}
__device__ __forceinline__ float b2f(u16 u) {
  union { unsigned u; float f; } c; c.u = ((unsigned)u) << 16;
  return c.f;
}

__device__ __forceinline__ void gl_lds16(const u16* g, u16* l) {
  __builtin_amdgcn_global_load_lds(
      (const __attribute__((address_space(1))) void*)g,
      (__attribute__((address_space(3))) void*)l, 16, 0, 0);
}

// ---------------- transpose + fp32->bf16 convert: W[K][N] -> WT[Npad][KApad] ---------
__global__ void tconv(const float* __restrict__ W, u16* __restrict__ WT,
                      int K, int N, int KApad, int Npad) {
  __shared__ float tile[32][33];
  int z = blockIdx.z;
  W += (size_t)z * K * N;
  WT += (size_t)z * Npad * KApad;
  int n0 = blockIdx.x * 32, k0 = blockIdx.y * 32;
  int tx = threadIdx.x, ty = threadIdx.y;
  for (int i = 0; i < 4; ++i) {
    int k = k0 + ty + i * 8, n = n0 + tx;
    tile[ty + i * 8][tx] = (k < K && n < N) ? W[(size_t)k * N + n] : 0.f;
  }
  __syncthreads();
  for (int i = 0; i < 4; ++i) {
    int n = n0 + ty + i * 8, k = k0 + tx;
    WT[(size_t)n * KApad + k] = f2b(tile[tx][ty + i * 8]);
  }
}

// ---------------- conditioning ----------------
__global__ void cond1(const int* __restrict__ ts, const float* __restrict__ Wt1,
                      const float* __restrict__ bt1, float* __restrict__ t1) {
  __shared__ float pe[512];
  int b = blockIdx.x, tid = threadIdx.x;
  float pos = (float)ts[b];
  int i2 = tid >> 1;
  float dv = expf(-0.0359778920780e0f * (float)i2);
  float ang = pos * dv;
  pe[tid] = (tid & 1) ? cosf(ang) : sinf(ang);
  __syncthreads();
  float acc = bt1[tid];
  for (int k = 0; k < 512; ++k) acc += pe[k] * Wt1[k * 512 + tid];
  t1[b * 512 + tid] = acc / (1.f + expf(-acc));  // silu
}

__global__ void cond2(const float* __restrict__ t1buf, const float* __restrict__ Wt2,
                      const float* __restrict__ bt2, const float* __restrict__ enc,
                      const float* __restrict__ Wtxt, const float* __restrict__ btxt,
                      float* __restrict__ emb) {
  __shared__ float a[512], m[512];
  int b = blockIdx.x, tid = threadIdx.x;
  a[tid] = t1buf[b * 512 + tid];
  float s = 0.f;
  for (int j = 0; j < 20; ++j) s += enc[((size_t)(b * 20 + j)) * 512 + tid];
  m[tid] = s * 0.05f;
  __syncthreads();
  float acc = bt2[tid] + btxt[tid];
  for (int k = 0; k < 512; ++k) acc += a[k] * Wt2[k * 512 + tid] + m[k] * Wtxt[k * 512 + tid];
  emb[b * 512 + tid] = acc;
}

// ---------------- rope table: [512][32] float2(cos,sin) ----------------
__global__ void rope_tab(float2* __restrict__ rt) {
  int idx = blockIdx.x * 256 + threadIdx.x;  // 16384
  int t = idx >> 5, i = idx & 31;
  float ang = (float)t * __expf(-0.28782313662f * (float)i);
  float sn, cn;
  sincosf(ang, &sn, &cn);
  rt[idx] = make_float2(cn, sn);
}

// ---------------- x fp32 -> bf16 with K-pad 150->192 ----------------
__global__ void xconv(const float* __restrict__ x, u16* __restrict__ xb) {
  int idx = blockIdx.x * 256 + threadIdx.x;  // 16384*192
  int mrow = idx / 192, kk = idx - mrow * 192;
  float v = (kk < 150) ? x[(size_t)mrow * 150 + kk] : 0.f;
  xb[idx] = f2b(v);
}

// ---------------- LayerNorm: one row per wave, shuffle-only ----------------
__global__ __launch_bounds__(256) void ln_kernel(const float* __restrict__ h,
                                                 const float* __restrict__ g,
                                                 const float* __restrict__ be,
                                                 u16* __restrict__ y) {
  int w = threadIdx.x >> 6, lane = threadIdx.x & 63;
  int row = blockIdx.x * 4 + w;
  const float* hr = h + (size_t)row * 512 + lane * 8;
  float4 a = ((const float4*)hr)[0], b4 = ((const float4*)hr)[1];
  float s = a.x + a.y + a.z + a.w + b4.x + b4.y + b4.z + b4.w;
  float s2 = a.x * a.x + a.y * a.y + a.z * a.z + a.w * a.w +
             b4.x * b4.x + b4.y * b4.y + b4.z * b4.z + b4.w * b4.w;
#pragma unroll
  for (int o = 32; o; o >>= 1) {
    s += __shfl_xor(s, o, 64);
    s2 += __shfl_xor(s2, o, 64);
  }
  float mean = s * (1.f / 512.f);
  float var = s2 * (1.f / 512.f) - mean * mean;
  float rs = rsqrtf(var + 1e-5f);
  const float4* gp = (const float4*)(g + lane * 8);
  const float4* bp = (const float4*)(be + lane * 8);
  float4 g0 = gp[0], g1 = gp[1], be0 = bp[0], be1 = bp[1];
  ushort4 o0, o1;
  o0.x = f2b((a.x - mean) * rs * g0.x + be0.x);
  o0.y = f2b((a.y - mean) * rs * g0.y + be0.y);
  o0.z = f2b((a.z - mean) * rs * g0.z + be0.z);
  o0.w = f2b((a.w - mean) * rs * g0.w + be0.w);
  o1.x = f2b((b4.x - mean) * rs * g1.x + be1.x);
  o1.y = f2b((b4.y - mean) * rs * g1.y + be1.y);
  o1.z = f2b((b4.z - mean) * rs * g1.z + be1.z);
  o1.w = f2b((b4.w - mean) * rs * g1.w + be1.w);
  ushort4* yp = (ushort4*)(y + (size_t)row * 512 + lane * 8);
  yp[0] = o0;
  yp[1] = o1;
}

// ---------------- flash attention v2, MFMA bf16 (proven R4/R7 version) ----------------
// grid (8 qtiles, 8 heads, 32 batch), 256 threads = 4 waves; wave w owns q-rows w*16..+15.
// qk layout: [b*512+t][1024] (Q cols 0..511 pre-scaled+rope'd, K cols 512..1023 rope'd).
// LDS: Qs 8K + KVs 16K (K then V^T) + Ps 16K = 40 KB -> 4 blocks/CU.
__global__ __launch_bounds__(256) void attn_mfma2(const u16* __restrict__ qk,
                                                  const u16* __restrict__ vt,
                                                  u16* __restrict__ o) {
  __shared__ u16 Qs[64 * 64];
  __shared__ u16 KVs[128 * 64];
  __shared__ u16 Ps[64 * 128];
  const int tid = threadIdx.x;
  const int qt = blockIdx.x, h = blockIdx.y, b = blockIdx.z;
  const int lane = tid & 63, w = tid >> 6;
  const int q = lane >> 4, c16 = lane & 15;

  // stage Q tile 64x64 (async)
  const size_t qbase = (size_t)(b * 512 + qt * 64) * 1024 + h * 64;
  {
    int row0 = tid >> 3, cs = tid & 7;
#pragma unroll
    for (int rep = 0; rep < 2; ++rep) {
      int r2 = rep * 32 + row0;
      int g = cs ^ (r2 & 7);
      gl_lds16(qk + qbase + (size_t)r2 * 1024 + g * 8, Qs + rep * 2048 + tid * 8);
    }
  }

  f32x4 o_acc[4];
  float m_st[4], l_st[4];
#pragma unroll
  for (int jd = 0; jd < 4; ++jd) o_acc[jd] = (f32x4){0.f, 0.f, 0.f, 0.f};
#pragma unroll
  for (int r = 0; r < 4; ++r) { m_st[r] = -1e30f; l_st[r] = 0.f; }

  const size_t kbase = (size_t)b * 512 * 1024 + 512 + h * 64;
  const size_t vtbase = ((size_t)(b * 8 + h) * 64) * 512;

  for (int kt = 0; kt < 4; ++kt) {
    if (kt) __syncthreads();  // prior PV reads of KVs/Ps done
    // stage K tile 128x64 (async)
    {
      int row0 = tid >> 3, cs = tid & 7;
#pragma unroll
      for (int rep = 0; rep < 4; ++rep) {
        int r2 = rep * 32 + row0;
        int g = cs ^ (r2 & 7);
        gl_lds16(qk + kbase + (size_t)(kt * 128 + r2) * 1024 + g * 8,
                 KVs + rep * 2048 + tid * 8);
      }
    }
    __syncthreads();  // K (and Q) visible

    // S = Q K^T  (1 m-tile x 8 n-tiles, K=64 -> 2 steps)
    f32x4 s_acc[8];
#pragma unroll
    for (int j = 0; j < 8; ++j) s_acc[j] = (f32x4){0.f, 0.f, 0.f, 0.f};
#pragma unroll
    for (int ka = 0; ka < 2; ++ka) {
      bf16x8 af, bf[8];
      {
        int row = w * 16 + c16;
        af = *(const bf16x8*)(Qs + row * 64 + (((ka * 4 + q) ^ (row & 7)) * 8));
      }
#pragma unroll
      for (int j = 0; j < 8; ++j) {
        int row = j * 16 + c16;
        bf[j] = *(const bf16x8*)(KVs + row * 64 + (((ka * 4 + q) ^ (row & 7)) * 8));
      }
#pragma unroll
      for (int j = 0; j < 8; ++j)
        s_acc[j] = __builtin_amdgcn_mfma_f32_16x16x32_bf16(af, bf[j], s_acc[j], 0, 0, 0);
    }
    __syncthreads();  // K reads done -> KVs reusable for V

    // stage V^T tile 64x128 (async); per rep = 256 lanes x 16B = 2048 u16
    {
      int vr0 = tid >> 4, cc = tid & 15;
#pragma unroll
      for (int rep = 0; rep < 4; ++rep) {
        int row = rep * 16 + vr0;
        int g2 = cc ^ (row & 15);
        gl_lds16(vt + vtbase + (size_t)row * 512 + kt * 128 + g2 * 8,
                 KVs + rep * 2048 + tid * 8);
      }
    }

    // online softmax in registers (scores pre-scaled via Q)
#pragma unroll
    for (int r = 0; r < 4; ++r) {
      float mx = s_acc[0][r];
#pragma unroll
      for (int j = 1; j < 8; ++j) mx = fmaxf(mx, s_acc[j][r]);
      mx = fmaxf(mx, __shfl_xor(mx, 1, 64));
      mx = fmaxf(mx, __shfl_xor(mx, 2, 64));
      mx = fmaxf(mx, __shfl_xor(mx, 4, 64));
      mx = fmaxf(mx, __shfl_xor(mx, 8, 64));
      float mn = fmaxf(m_st[r], mx);
      float al = __expf(m_st[r] - mn);
      m_st[r] = mn;
      float sum = 0.f;
#pragma unroll
      for (int j = 0; j < 8; ++j) {
        float p = __expf(s_acc[j][r] - mn);
        s_acc[j][r] = p;
        sum += p;
      }
      sum += __shfl_xor(sum, 1, 64);
      sum += __shfl_xor(sum, 2, 64);
      sum += __shfl_xor(sum, 4, 64);
      sum += __shfl_xor(sum, 8, 64);
      l_st[r] = l_st[r] * al + sum;
#pragma unroll
      for (int jd = 0; jd < 4; ++jd) o_acc[jd][r] *= al;
    }

    // write P (bf16, swizzled A-layout source)
#pragma unroll
    for (int j = 0; j < 8; ++j)
#pragma unroll
      for (int r = 0; r < 4; ++r) {
        int prow = w * 16 + q * 4 + r;
        int col = j * 16 + c16;
        int cp = col >> 3;
        Ps[prow * 128 + ((cp ^ (prow & 15)) * 8) + (col & 7)] = f2b(s_acc[j][r]);
      }
    __syncthreads();  // P written, V visible

    // O += P V  (128 keys -> 4 steps)
#pragma unroll
    for (int s = 0; s < 4; ++s) {
      bf16x8 af, bv[4];
      {
        int row = w * 16 + c16;
        af = *(const bf16x8*)(Ps + row * 128 + (((s * 4 + q) ^ (row & 15)) * 8));
      }
#pragma unroll
      for (int jd = 0; jd < 4; ++jd) {
        int row = jd * 16 + c16;
        bv[jd] = *(const bf16x8*)(KVs + row * 128 + (((s * 4 + q) ^ (row & 15)) * 8));
      }
#pragma unroll
      for (int jd = 0; jd < 4; ++jd)
        o_acc[jd] = __builtin_amdgcn_mfma_f32_16x16x32_bf16(af, bv[jd], o_acc[jd], 0, 0, 0);
    }
  }

  // epilogue: normalize and store
#pragma unroll
  for (int r = 0; r < 4; ++r) {
    float inv = 1.f / l_st[r];
    int trow = qt * 64 + w * 16 + q * 4 + r;
#pragma unroll
    for (int jd = 0; jd < 4; ++jd)
      o[(size_t)(b * 512 + trow) * 512 + h * 64 + jd * 16 + c16] = f2b(o_acc[jd][r] * inv);
  }
}

// ---------------- bf16 MFMA GEMM, 128x128 tile, XCD-swizzled flat grid ------
// grid = nx * 128 blocks (1-D). nx = number of 128-col N-tiles.
// Swizzle: the nx blocks sharing an M-band get the same (bid & 7) residue ->
// same XCD under round-robin, so the A-band is fetched into one XCD's L2 once.
// MODE 0: fp32 out = acc + bias + emb[row/512]
// MODE 2: fp32 out = aux(h) + acc + bias
// MODE 3: bf16 out = gelu(acc + bias)  (tanh approx, sigmoid form)
// MODE 4: fp32 out[row*150+col] = acc + bias, col<150
// MODE 5: qkv fused rope/V^T (aux = rope table, aux2 = V^T buffer)
// MODE 6: MODE 2 + bf16 copy into aux2
template <int MODE>
__global__ __launch_bounds__(256) void gemm_bf16(
    const u16* __restrict__ A, const u16* __restrict__ BT,
    const float* __restrict__ bias, const float* aux, void* aux2, void* Cout,
    int KA, int ldc, int nx) {
  __shared__ u16 As[128 * 64];
  __shared__ u16 Bs[128 * 64];
  const int tid = threadIdx.x;
  int bid = blockIdx.x;
  int rr = bid & 7, gg = bid >> 3;
  int xN = gg % nx, yM = rr + 8 * (gg / nx);
  const int tileN = xN * 128;
  const int tileM = yM * 128;
  const int lane = tid & 63, w = tid >> 6;
  const int mw = (w >> 1) * 64, nw = (w & 1) * 64;
  const int q = lane >> 4, c16 = lane & 15;

  f32x4 acc[4][4];
#pragma unroll
  for (int i = 0; i < 4; ++i)
#pragma unroll
    for (int j = 0; j < 4; ++j) acc[i][j] = (f32x4){0.f, 0.f, 0.f, 0.f};

  const int rowA0 = tid >> 3;  // 0..31
  const int cs = tid & 7;
  const int KT = KA >> 6;
  for (int kt = 0; kt < KT; ++kt) {
    __syncthreads();
#pragma unroll
    for (int rep = 0; rep < 4; ++rep) {
      int row = rep * 32 + rowA0;
      int g = cs ^ (row & 7);
      gl_lds16(A + (size_t)(tileM + row) * KA + kt * 64 + g * 8,
               (u16*)((char*)As + rep * 4096 + tid * 16));
    }
#pragma unroll
    for (int rep = 0; rep < 4; ++rep) {
      int row = rep * 32 + rowA0;
      int g = cs ^ (row & 7);
      gl_lds16(BT + (size_t)(tileN + row) * KA + kt * 64 + g * 8,
               (u16*)((char*)Bs + rep * 4096 + tid * 16));
    }
    __syncthreads();
#pragma unroll
    for (int ks = 0; ks < 2; ++ks) {
      bf16x8 af[4], bfr[4];
#pragma unroll
      for (int i = 0; i < 4; ++i) {
        int m = mw + i * 16 + c16;
        int ca = (ks * 4 + q) ^ (m & 7);
        af[i] = *(const bf16x8*)((const char*)As + m * 128 + ca * 16);
        int n = nw + i * 16 + c16;
        int cb = (ks * 4 + q) ^ (n & 7);
        bfr[i] = *(const bf16x8*)((const char*)Bs + n * 128 + cb * 16);
      }
#pragma unroll
      for (int i = 0; i < 4; ++i)
#pragma unroll
        for (int j = 0; j < 4; ++j)
          acc[i][j] = __builtin_amdgcn_mfma_f32_16x16x32_bf16(af[i], bfr[j], acc[i][j], 0, 0, 0);
    }
  }

  if (MODE == 5) {
    // fused qkv epilogue: rope on Q (scaled) and K; transpose-store V.
    const float2* rt = (const float2*)aux;
    u16* qk = (u16*)Cout;
    u16* vtp = (u16*)aux2;
#pragma unroll
    for (int i = 0; i < 4; ++i) {
      int row = tileM + mw + i * 16 + q * 4;
      int bb = row >> 9, t0 = row & 511;
#pragma unroll
      for (int jp = 0; jp < 2; ++jp) {
        int colA = tileN + nw + jp * 16 + c16;
        if (colA < 1024) {
          int colB = colA + 32;
          int d31 = colA & 31;
          float scl = (colA < 512) ? 0.125f : 1.f;
          float bA = bias[colA], bB = bias[colB];
#pragma unroll
          for (int r = 0; r < 4; ++r) {
            float2 cs2 = rt[(t0 + r) * 32 + d31];
            float x1 = acc[i][jp][r] + bA;
            float x2 = acc[i][jp + 2][r] + bB;
            size_t rbase = (size_t)(row + r) * 1024;
            qk[rbase + colA] = f2b((x1 * cs2.x - x2 * cs2.y) * scl);
            qk[rbase + colB] = f2b((x2 * cs2.x + x1 * cs2.y) * scl);
          }
        } else {
#pragma unroll
          for (int jj = jp; jj < 4; jj += 2) {
            int col = tileN + nw + jj * 16 + c16;
            int hh = (col - 1024) >> 6, d = col & 63;
            float bv2 = bias[col];
            ushort4 pk;
            pk.x = f2b(acc[i][jj][0] + bv2);
            pk.y = f2b(acc[i][jj][1] + bv2);
            pk.z = f2b(acc[i][jj][2] + bv2);
            pk.w = f2b(acc[i][jj][3] + bv2);
            *(ushort4*)(vtp + ((size_t)((bb * 8 + hh) * 64 + d)) * 512 + t0) = pk;
          }
        }
      }
    }
    return;
  }

  // generic epilogues
#pragma unroll
  for (int i = 0; i < 4; ++i) {
#pragma unroll
    for (int j = 0; j < 4; ++j) {
      int col = tileN + nw + j * 16 + c16;
      float bv = (MODE == 4) ? 0.f : bias[col];
#pragma unroll
      for (int r = 0; r < 4; ++r) {
        int row = tileM + mw + i * 16 + q * 4 + r;
        float v = acc[i][j][r] + bv;
        if (MODE == 0) {
          ((float*)Cout)[(size_t)row * ldc + col] = v + aux[(row >> 9) * 512 + col];
        } else if (MODE == 2) {
          size_t idx = (size_t)row * ldc + col;
          ((float*)Cout)[idx] = aux[idx] + v;
        } else if (MODE == 3) {
          // gelu tanh-approx in sigmoid form: v * sigma(1.5957691*v*(1+0.044715 v^2))
          float u = v * v;
          float p = __builtin_fmaf(0.044715f, u, 1.0f);
          float t2 = v * p;
          float e = __expf(-1.59576912f * t2);
          float r2 = __builtin_amdgcn_rcpf(1.0f + e);
          ((u16*)Cout)[(size_t)row * ldc + col] = f2b(v * r2);
        } else if (MODE == 4) {
          if (col < 150) ((float*)Cout)[(size_t)row * 150 + col] = acc[i][j][r] + bias[col];
        } else if (MODE == 6) {
          size_t idx = (size_t)row * ldc + col;
          float v2 = aux[idx] + v;
          ((float*)Cout)[idx] = v2;
          ((u16*)aux2)[idx] = f2b(v2);
        }
      }
    }
  }
}

// ---------------- launch ----------------
extern "C" void kernel_launch(void* const* d_in, const int* in_sizes, int n_in,
                              void* d_out, int out_size, void* d_ws, size_t ws_size,
                              hipStream_t stream) {
  const float* x = (const float*)d_in[0];
  const int* tsteps = (const int*)d_in[1];
  const float* enc = (const float*)d_in[2];
  const float* W_in = (const float*)d_in[3];
  const float* b_in = (const float*)d_in[4];
  const float* W_t1 = (const float*)d_in[5];
  const float* b_t1 = (const float*)d_in[6];
  const float* W_t2 = (const float*)d_in[7];
  const float* b_t2 = (const float*)d_in[8];
  const float* W_txt = (const float*)d_in[9];
  const float* b_txt = (const float*)d_in[10];
  const float* ln1_g = (const float*)d_in[11];
  const float* ln1_b = (const float*)d_in[12];
  const float* Wqkv = (const float*)d_in[13];
  const float* bqkv = (const float*)d_in[14];
  const float* Wo = (const float*)d_in[15];
  const float* bo = (const float*)d_in[16];
  const float* ln2_g = (const float*)d_in[17];
  const float* ln2_b = (const float*)d_in[18];
  const float* W1 = (const float*)d_in[19];
  const float* b1 = (const float*)d_in[20];
  const float* W2 = (const float*)d_in[21];
  const float* b2 = (const float*)d_in[22];
  const float* W_out = (const float*)d_in[23];
  const float* b_out = (const float*)d_in[24];

  char* ws = (char*)d_ws;
  u16* WT_in = (u16*)(ws + 0);              // 512*192
  u16* WT_qkv = (u16*)(ws + 196608);        // 8*1536*512
  u16* WT_o = (u16*)(ws + 12779520);        // 8*512*512
  u16* WT_1 = (u16*)(ws + 16973824);        // 8*2048*512
  u16* WT_2 = (u16*)(ws + 33751040);        // 8*512*2048
  u16* WT_out = (u16*)(ws + 50528256);      // 256*512
  u16* xb = (u16*)(ws + 50790400);          // 16384*192
  float* hf = (float*)(ws + 57081856);      // 16384*512 f32
  u16* yb = (u16*)(ws + 90636288);          // 16384*512
  u16* qkvb = (u16*)(ws + 107413504);       // 16384*1024 (Q,K rope'd); tail reused:
  float2* rtab = (float2*)(ws + 107413504 + 33554432);  // 512*32 float2 = 128 KB
  u16* ob = (u16*)(ws + 157745152);         // 16384*512
  u16* ffb = (u16*)(ws + 174522368);        // 16384*2048
  u16* hb = (u16*)(ws + 241631232);         // 16384*512 (final h bf16; idle during layers)
  u16* vtb = hb;                            // aliased: V^T [b][h][64][512], layer-loop only
  float* embf = (float*)(ws + 258408448);   // 32*512 f32
  float* t1c = (float*)(ws + 258473984);    // 32*512 f32

  dim3 tb(32, 8);
  tconv<<<dim3(16, 6, 1), tb, 0, stream>>>(W_in, WT_in, 150, 512, 192, 512);
  tconv<<<dim3(48, 16, 8), tb, 0, stream>>>(Wqkv, WT_qkv, 512, 1536, 512, 1536);
  tconv<<<dim3(16, 16, 8), tb, 0, stream>>>(Wo, WT_o, 512, 512, 512, 512);
  tconv<<<dim3(64, 16, 8), tb, 0, stream>>>(W1, WT_1, 512, 2048, 512, 2048);
  tconv<<<dim3(16, 64, 8), tb, 0, stream>>>(W2, WT_2, 2048, 512, 2048, 512);
  tconv<<<dim3(8, 16, 1), tb, 0, stream>>>(W_out, WT_out, 512, 150, 512, 256);

  cond1<<<32, 512, 0, stream>>>(tsteps, W_t1, b_t1, t1c);
  cond2<<<32, 512, 0, stream>>>(t1c, W_t2, b_t2, enc, W_txt, b_txt, embf);
  rope_tab<<<64, 256, 0, stream>>>(rtab);
  xconv<<<12288, 256, 0, stream>>>(x, xb);

  // h = x @ W_in + b_in + emb
  gemm_bf16<0><<<4 * 128, 256, 0, stream>>>(xb, WT_in, b_in, embf, nullptr, hf, 192, 512, 4);

  for (int l = 0; l < 8; ++l) {
    ln_kernel<<<4096, 256, 0, stream>>>(hf, ln1_g + l * 512, ln1_b + l * 512, yb);
    gemm_bf16<5><<<12 * 128, 256, 0, stream>>>(yb, WT_qkv + (size_t)l * 1536 * 512,
                                               bqkv + l * 1536, (const float*)rtab,
                                               vtb, qkvb, 512, 1024, 12);
    attn_mfma2<<<dim3(8, 8, 32), 256, 0, stream>>>(qkvb, vtb, ob);
    gemm_bf16<2><<<4 * 128, 256, 0, stream>>>(ob, WT_o + (size_t)l * 512 * 512,
                                              bo + l * 512, hf, nullptr, hf, 512, 512, 4);
    ln_kernel<<<4096, 256, 0, stream>>>(hf, ln2_g + l * 512, ln2_b + l * 512, yb);
    gemm_bf16<3><<<16 * 128, 256, 0, stream>>>(yb, WT_1 + (size_t)l * 2048 * 512,
                                               b1 + l * 2048, nullptr, nullptr, ffb, 512, 2048, 16);
    if (l < 7) {
      gemm_bf16<2><<<4 * 128, 256, 0, stream>>>(ffb, WT_2 + (size_t)l * 512 * 2048,
                                                b2 + l * 512, hf, nullptr, hf, 2048, 512, 4);
    } else {
      gemm_bf16<6><<<4 * 128, 256, 0, stream>>>(ffb, WT_2 + (size_t)l * 512 * 2048,
                                                b2 + l * 512, hf, hb, hf, 2048, 512, 4);
    }
  }

  gemm_bf16<4><<<2 * 128, 256, 0, stream>>>(hb, WT_out, b_out, nullptr, nullptr, d_out, 512, 150, 2);
}